// Round 9
// baseline (429.483 us; speedup 1.0000x reference)
//
#include <hip/hip_runtime.h>
#include <hip/hip_cooperative_groups.h>
#include <cstddef>
#include <cstdint>

namespace cg = cooperative_groups;

namespace {

typedef _Float16 half8 __attribute__((ext_vector_type(8)));
typedef _Float16 half4 __attribute__((ext_vector_type(4)));
typedef float f32x4 __attribute__((ext_vector_type(4)));

constexpr int Bn   = 4;
constexpr int Ln   = 1024;
constexpr int INn  = 256;
constexpr int DMn  = 1024;
constexpr int DSn  = 16;
constexpr int DCn  = 4;
constexpr int DIn  = 2048;
constexpr int DTRn = 64;
constexpr int XPW  = DTRn + DSn;    // 80
constexpr int NCHUNK = 64;
constexpr int CHUNK  = Ln / NCHUNK; // 16
constexpr int WCH  = 32;
constexpr int ML   = Bn * Ln;       // 4096

// phase task counts
constexpr int T_PREP = 6017;
constexpr int T_WFOLD = 256;
constexpr int T_WFSUM = ML * INn / 4 / 256;  // 1024 blocks of 256 quads
constexpr int T_UPRE = 512;
constexpr int T_CONVZ = 1056;
constexpr int T_DTB = 256;
constexpr int T_DTBSUM = 1296;
constexpr int T_DELTA = 512;
constexpr int T_SCAN = 2048;
constexpr int T_COMB = 512;

__device__ __forceinline__ float silu_(float x) { return x / (1.f + __expf(-x)); }
__device__ __forceinline__ float softplus_(float x) {
    return fmaxf(x, 0.f) + __logf(1.f + __expf(-fabsf(x)));
}

struct MegaP {
    const float *x, *b_emb, *in_proj, *conv_w, *conv_b, *x_proj, *dt_b, *A_log, *Dp,
                *out_w, *fc_w, *fc_b, *W_emb, *dt_w;
    float* out;
    _Float16 *xh, *iph, *dtwh, *W_embT, *xp_h, *upreh, *uh, *deltah, *dtBh, *Wfoldh;
    float *wfoldP, *skp, *cS;
    _Float16 *cH;
    float *wp, *badd, *zlast, *Clast;
};

// 128x128 MFMA tile, 4 waves, BK=32, global_load_lds staging.
// EPI 0: fp32 partial (Pout stride N); EPI 1: fp16 + bias; EPI 2: fp16 + bias + softplus
template<int EPI>
__device__ __forceinline__ void gemm_tile(
    const _Float16* __restrict__ A, int lda,
    const _Float16* __restrict__ Bw, int ldb,
    int m0, int n0, int kbeg, int kend, int N,
    float* __restrict__ Pout,
    _Float16* __restrict__ Ch, int ldc,
    const float* __restrict__ bias,
    _Float16* As, _Float16* Bs, int tid)
{
    const int lane = tid & 63;
    const int wid  = tid >> 6;
    const int wm = wid >> 1, wn = wid & 1;
    f32x4 acc[4][4] = {};
    for (int k0 = kbeg; k0 < kend; k0 += 32) {
        #pragma unroll
        for (int i = 0; i < 2; ++i) {
            const int off = tid * 16 + i * 4096;
            const int row = off >> 6;
            const int ch  = (off & 63) >> 1;
            __builtin_amdgcn_global_load_lds(
                (const __attribute__((address_space(1))) void*)(A + (size_t)(m0 + row) * lda + k0 + ch),
                (__attribute__((address_space(3))) void*)(As + (off >> 1)), 16, 0, 0);
            __builtin_amdgcn_global_load_lds(
                (const __attribute__((address_space(1))) void*)(Bw + (size_t)(n0 + row) * ldb + k0 + ch),
                (__attribute__((address_space(3))) void*)(Bs + (off >> 1)), 16, 0, 0);
        }
        __syncthreads();
        const int ar = lane & 15;
        const int kq = (lane >> 4) * 8;
        half8 af[4], bf[4];
        #pragma unroll
        for (int i = 0; i < 4; ++i) af[i] = *(const half8*)(As + (wm * 64 + i * 16 + ar) * 32 + kq);
        #pragma unroll
        for (int j = 0; j < 4; ++j) bf[j] = *(const half8*)(Bs + (wn * 64 + j * 16 + ar) * 32 + kq);
        #pragma unroll
        for (int i = 0; i < 4; ++i)
            #pragma unroll
            for (int j = 0; j < 4; ++j)
                acc[i][j] = __builtin_amdgcn_mfma_f32_16x16x32_f16(af[i], bf[j], acc[i][j], 0, 0, 0);
        __syncthreads();
    }
    const int cr = (lane >> 4) * 4;
    const int cn = lane & 15;
    #pragma unroll
    for (int i = 0; i < 4; ++i)
        #pragma unroll
        for (int j = 0; j < 4; ++j) {
            const int n = n0 + wn * 64 + j * 16 + cn;
            if (n < N) {
                #pragma unroll
                for (int r = 0; r < 4; ++r) {
                    const int m = m0 + wm * 64 + i * 16 + cr + r;
                    if (EPI == 0) {
                        Pout[(size_t)m * N + n] = acc[i][j][r];
                    } else {
                        float v = acc[i][j][r] + bias[n];
                        if (EPI == 2) v = softplus_(v);
                        Ch[(size_t)m * ldc + n] = (_Float16)v;
                    }
                }
            }
        }
}

// ====================== per-task phase bodies (shared by both paths) ======================
__device__ __forceinline__ void ph_prep(const MegaP& p, int task, int tid, float* shf) {
    if (task < 4096) {
        const int n = task;
        const float4 v = ((const float4*)p.in_proj)[n * 256 + tid];
        ((half4*)p.iph)[n * 256 + tid] =
            half4{(_Float16)v.x, (_Float16)v.y, (_Float16)v.z, (_Float16)v.w};
        const float4 bv = ((const float4*)p.b_emb)[tid];
        float s = v.x * bv.x + v.y * bv.y + v.z * bv.z + v.w * bv.w;
        for (int off = 32; off > 0; off >>= 1) s += __shfl_down(s, off);
        if ((tid & 63) == 0) shf[tid >> 6] = s;
        __syncthreads();
        if (tid == 0) p.badd[n] = shf[0] + shf[1] + shf[2] + shf[3];
    } else if (task < 5248) {
        const float* in; _Float16* outp; int i;
        if (task < 5120) { in = p.x;    outp = p.xh;   i = (task - 4096) * 256 + tid; }
        else             { in = p.dt_w; outp = p.dtwh; i = (task - 5120) * 256 + tid; }
        const float4 v = ((const float4*)in)[i];
        ((half4*)outp)[i] = half4{(_Float16)v.x, (_Float16)v.y, (_Float16)v.z, (_Float16)v.w};
    } else if (task < 5504) {
        const int bx = task - 5248;
        const int m0 = (bx & 31) * 32, c0 = (bx >> 5) * 32;
        const int lc = tid & 31, lr = tid >> 5;
        float (*tile)[33] = (float(*)[33])(void*)shf;
        #pragma unroll
        for (int ph = 0; ph < 4; ++ph)
            tile[lr + ph * 8][lc] = p.W_emb[(size_t)(m0 + lr + ph * 8) * INn + c0 + lc];
        __syncthreads();
        #pragma unroll
        for (int ph = 0; ph < 4; ++ph)
            p.W_embT[(size_t)(c0 + lr + ph * 8) * DMn + m0 + lc] = (_Float16)tile[lc][lr + ph * 8];
    } else if (task < 5760) {
        const int i = (task - 5504) * 256 + tid;
        const int r = i >> 9;
        const int c4 = i & 511;
        half4 h;
        if (r < XPW) {
            const float4 v = ((const float4*)(p.x_proj + (size_t)r * DIn))[c4];
            h = half4{(_Float16)v.x, (_Float16)v.y, (_Float16)v.z, (_Float16)v.w};
        } else {
            h = half4{(_Float16)0.f, (_Float16)0.f, (_Float16)0.f, (_Float16)0.f};
        }
        ((half4*)(p.xp_h + (size_t)r * DIn))[c4] = h;
    } else if (task < 6016) {
        const int bx = task - 5760;
        const int d = (bx & 7) * 256 + tid;
        const int c = bx >> 3;
        const int mstep = DMn / WCH;
        float s = 0.f;
        for (int m = c * mstep; m < (c + 1) * mstep; ++m)
            s += p.fc_w[m] * p.out_w[(size_t)m * DIn + d];
        p.wp[(size_t)c * DIn + d] = s;
    } else {
        if (tid < Bn) p.out[tid] = p.fc_b[0];
    }
}

__device__ __forceinline__ void ph_wfold(const MegaP& p, int task, int tid,
                                         _Float16* As, _Float16* Bs) {
    const int sk = task >> 6;
    const int mt = (task & 63) >> 1;
    const int nt = task & 1;
    gemm_tile<0>(p.iph, DMn, p.W_embT, DMn, mt * 128, nt * 128,
                 sk * 256, sk * 256 + 256, INn,
                 p.wfoldP + (size_t)sk * ML * INn, nullptr, 0, nullptr, As, Bs, tid);
}

__device__ __forceinline__ void ph_wfoldsum(const MegaP& p, int i) {
    float4 s = ((const float4*)p.wfoldP)[i];
    #pragma unroll
    for (int k = 1; k < 4; ++k) {
        const float4 v = ((const float4*)(p.wfoldP + (size_t)k * ML * INn))[i];
        s.x += v.x; s.y += v.y; s.z += v.z; s.w += v.w;
    }
    ((half4*)p.Wfoldh)[i] = half4{(_Float16)s.x, (_Float16)s.y, (_Float16)s.z, (_Float16)s.w};
}

__device__ __forceinline__ void ph_upre(const MegaP& p, int task, int tid,
                                        _Float16* As, _Float16* Bs) {
    gemm_tile<1>(p.xh, INn, p.Wfoldh, INn, (task >> 4) * 128, (task & 15) * 128,
                 0, 256, DIn, nullptr, p.upreh, DIn, p.badd, As, Bs, tid);
}

__device__ __forceinline__ void ph_convz(const MegaP& p, int task, int tid) {
    if (task < 1024) {
        const int b  = task >> 8;
        const int t0 = (task & 255) * 4;
        const int d0 = tid * 8;
        const size_t rowbase = ((size_t)b * Ln + t0) * DIn + d0;
        half8 hzero;
        #pragma unroll
        for (int q = 0; q < 8; ++q) hzero[q] = (_Float16)0.f;
        half8 rows[7];
        if (t0 >= 3) {
            #pragma unroll
            for (int r = 0; r < 7; ++r)
                rows[r] = *(const half8*)(p.upreh + rowbase + (ptrdiff_t)(r - 3) * DIn);
        } else {
            #pragma unroll
            for (int r = 0; r < 7; ++r) {
                const int t = t0 - 3 + r;
                rows[r] = (t >= 0) ? *(const half8*)(p.upreh + rowbase + (ptrdiff_t)(r - 3) * DIn) : hzero;
            }
        }
        f32x4 cwq[8];
        float cbv[8];
        #pragma unroll
        for (int q = 0; q < 8; ++q) {
            cwq[q] = *(const f32x4*)(p.conv_w + (size_t)(d0 + q) * DCn);
            cbv[q] = p.conv_b[d0 + q];
        }
        #pragma unroll
        for (int s = 0; s < 4; ++s) {
            half8 o;
            #pragma unroll
            for (int q = 0; q < 8; ++q) {
                float acc = cbv[q];
                #pragma unroll
                for (int j = 0; j < DCn; ++j) acc += (float)rows[s + j][q] * cwq[q][j];
                o[q] = (_Float16)silu_(acc);
            }
            *(half8*)(p.uh + rowbase + (size_t)s * DIn) = o;
        }
    } else {
        const int t = (task - 1024) * 256 + tid;   // 8192 = 2048 j x 4 b
        const int j = t & (DIn - 1), b = t >> 11;
        const float4* x4 = (const float4*)(p.x + ((size_t)b * Ln + (Ln - 1)) * INn);
        const half4* w4 = (const half4*)(p.Wfoldh + (size_t)(DIn + j) * INn);
        float s = 0.f;
        #pragma unroll 8
        for (int q = 0; q < 64; ++q) {
            const float4 xv = x4[q];
            const half4 wv = w4[q];
            s += (float)wv[0] * xv.x + (float)wv[1] * xv.y
               + (float)wv[2] * xv.z + (float)wv[3] * xv.w;
        }
        p.zlast[(size_t)b * DIn + j] = s + p.badd[DIn + j];
    }
}

__device__ __forceinline__ void ph_dtb(const MegaP& p, int task, int tid,
                                       _Float16* As, _Float16* Bs) {
    const int sk = task >> 5;
    const int mt = task & 31;
    gemm_tile<0>(p.uh, DIn, p.xp_h, DIn, mt * 128, 0,
                 sk * 256, sk * 256 + 256, XPW,
                 p.skp + (size_t)sk * ML * XPW, nullptr, 0, nullptr, As, Bs, tid);
}

__device__ __forceinline__ void ph_dtbsum(const MegaP& p, int task, int tid) {
    if (task < 1280) {
        const int i = task * 256 + tid;
        float s = 0.f;
        #pragma unroll
        for (int k = 0; k < 8; ++k) s += p.skp[(size_t)k * (ML * XPW) + i];
        p.dtBh[i] = (_Float16)s;
    } else {
        const int wave = tid >> 6, lane = tid & 63;
        const int t = (task - 1280) * 4 + wave;   // 64 tasks
        const int s_idx = t & 15, b = t >> 4;
        const _Float16* ur = p.uh + ((size_t)b * Ln + (Ln - 1)) * DIn;
        const float* w = p.x_proj + (size_t)(XPW + s_idx) * DIn;
        float s = 0.f;
        for (int k = lane; k < DIn; k += 64) s += (float)ur[k] * w[k];
        for (int off = 32; off > 0; off >>= 1) s += __shfl_down(s, off);
        if (lane == 0) p.Clast[b * DSn + s_idx] = s;
    }
}

__device__ __forceinline__ void ph_delta(const MegaP& p, int task, int tid,
                                         _Float16* As, _Float16* Bs) {
    gemm_tile<2>(p.dtBh, XPW, p.dtwh, DTRn, (task >> 4) * 128, (task & 15) * 128,
                 0, 64, DIn, nullptr, p.deltah, DIn, p.dt_b, As, Bs, tid);
}

__device__ __forceinline__ void ph_scan(const MegaP& p, int task, int tid) {
    const int dgrp = task & 7;
    const int c = (task >> 3) & 63;
    const int b = task >> 9;
    const int d = dgrp * 256 + tid;
    float A[DSn], h[DSn];
    const float4* al = (const float4*)(p.A_log + (size_t)d * DSn);
    #pragma unroll
    for (int q = 0; q < 4; ++q) {
        const float4 v = al[q];
        A[q * 4 + 0] = -__expf(v.x); A[q * 4 + 1] = -__expf(v.y);
        A[q * 4 + 2] = -__expf(v.z); A[q * 4 + 3] = -__expf(v.w);
        h[q * 4 + 0] = 0.f; h[q * 4 + 1] = 0.f; h[q * 4 + 2] = 0.f; h[q * 4 + 3] = 0.f;
    }
    const float A0 = A[0];
    bool structured = true;
    #pragma unroll
    for (int s = 1; s < DSn; ++s)
        structured = structured && (fabsf(A[s] - (float)(s + 1) * A0) <= 1e-4f * (s + 1));
    float Ssum = 0.f;
    const size_t base = ((size_t)b * Ln + (size_t)c * CHUNK) * DIn + d;
    const _Float16* Bp = p.dtBh + ((size_t)b * Ln + (size_t)c * CHUNK) * XPW + DTRn;
    if (structured) {
        #pragma unroll 4
        for (int tt = 0; tt < CHUNK; ++tt) {
            const float dl = (float)p.deltah[base + (size_t)tt * DIn];
            const float uu = (float)p.uh[base + (size_t)tt * DIn];
            const float du = dl * uu;
            Ssum += dl;
            const half8 bv0 = *(const half8*)(Bp + tt * XPW);
            const half8 bv1 = *(const half8*)(Bp + tt * XPW + 8);
            float Bv[DSn];
            #pragma unroll
            for (int q = 0; q < 8; ++q) { Bv[q] = (float)bv0[q]; Bv[8 + q] = (float)bv1[q]; }
            const float e1 = __expf(dl * A0);
            const float e2 = e1 * e1, e4 = e2 * e2, e8 = e4 * e4;
            float E[DSn];
            E[0] = e1;      E[1] = e2;      E[2] = e2 * e1;  E[3] = e4;
            E[4] = e4 * e1; E[5] = e4 * e2; E[6] = E[5] * e1; E[7] = e8;
            E[8] = e8 * e1; E[9] = e8 * e2; E[10] = E[9] * e1; E[11] = e8 * e4;
            E[12] = E[11] * e1; E[13] = E[11] * e2; E[14] = E[13] * e1; E[15] = e8 * e8;
            #pragma unroll
            for (int s = 0; s < DSn; ++s) h[s] = E[s] * h[s] + du * Bv[s];
        }
    } else {
        #pragma unroll 4
        for (int tt = 0; tt < CHUNK; ++tt) {
            const float dl = (float)p.deltah[base + (size_t)tt * DIn];
            const float uu = (float)p.uh[base + (size_t)tt * DIn];
            const float du = dl * uu;
            Ssum += dl;
            const half8 bv0 = *(const half8*)(Bp + tt * XPW);
            const half8 bv1 = *(const half8*)(Bp + tt * XPW + 8);
            float Bv[DSn];
            #pragma unroll
            for (int q = 0; q < 8; ++q) { Bv[q] = (float)bv0[q]; Bv[8 + q] = (float)bv1[q]; }
            #pragma unroll
            for (int s = 0; s < DSn; ++s) h[s] = __expf(dl * A[s]) * h[s] + du * Bv[s];
        }
    }
    const size_t cidx = ((size_t)b * NCHUNK + c) * DIn + d;
    p.cS[cidx] = Ssum;
    half8 o0, o1;
    #pragma unroll
    for (int q = 0; q < 8; ++q) { o0[q] = (_Float16)h[q]; o1[q] = (_Float16)h[8 + q]; }
    *(half8*)(p.cH + cidx * DSn) = o0;
    *(half8*)(p.cH + cidx * DSn + 8) = o1;
}

__device__ __forceinline__ void ph_combine(const MegaP& p, int task, int tid, float* accs) {
    const int dgrp = task & 127;
    const int b = task >> 7;
    const int s = tid & 15;
    const int d = dgrp * 16 + (tid >> 4);
    const float A = -__expf(p.A_log[(size_t)d * DSn + s]);
    float h = 0.f;
    const size_t cb0 = (size_t)b * NCHUNK;
    for (int c = 0; c < NCHUNK; ++c) {
        const size_t cidx = (cb0 + c) * DIn + d;
        h = __expf(A * p.cS[cidx]) * h + (float)p.cH[cidx * DSn + s];
    }
    float y = h * p.Clast[b * DSn + s];
    y += __shfl_xor(y, 1);
    y += __shfl_xor(y, 2);
    y += __shfl_xor(y, 4);
    y += __shfl_xor(y, 8);
    if (s == 0) {
        const float ul = (float)p.uh[((size_t)b * Ln + (Ln - 1)) * DIn + d];
        float yy = y + p.Dp[d] * ul;
        yy *= silu_(p.zlast[(size_t)b * DIn + d]);
        float w = 0.f;
        #pragma unroll
        for (int c = 0; c < WCH; ++c) w += p.wp[(size_t)c * DIn + d];
        accs[tid >> 4] = yy * w;
    }
    __syncthreads();
    if (tid == 0) {
        float t = 0.f;
        #pragma unroll
        for (int i = 0; i < 16; ++i) t += accs[i];
        atomicAdd(&p.out[b], t);
    }
}

// ====================== cooperative mega kernel ======================
__global__ __launch_bounds__(256, 2)
void mamba_mega(MegaP p) {
    __shared__ _Float16 As[128 * 32];
    __shared__ _Float16 Bs[128 * 32];
    const int tid = threadIdx.x;
    const int bid = blockIdx.x;
    const int nb  = gridDim.x;
    cg::grid_group grid = cg::this_grid();

    for (int t = bid; t < T_PREP; t += nb) { ph_prep(p, t, tid, (float*)As); __syncthreads(); }
    grid.sync();
    for (int t = bid; t < T_WFOLD; t += nb) ph_wfold(p, t, tid, As, Bs);
    grid.sync();
    for (int i = bid * 256 + tid; i < ML * INn / 4; i += nb * 256) ph_wfoldsum(p, i);
    grid.sync();
    for (int t = bid; t < T_UPRE; t += nb) ph_upre(p, t, tid, As, Bs);
    grid.sync();
    for (int t = bid; t < T_CONVZ; t += nb) ph_convz(p, t, tid);
    grid.sync();
    for (int t = bid; t < T_DTB; t += nb) ph_dtb(p, t, tid, As, Bs);
    grid.sync();
    for (int t = bid; t < T_DTBSUM; t += nb) ph_dtbsum(p, t, tid);
    grid.sync();
    for (int t = bid; t < T_DELTA; t += nb) ph_delta(p, t, tid, As, Bs);
    grid.sync();
    for (int t = bid; t < T_SCAN; t += nb) ph_scan(p, t, tid);
    grid.sync();
    for (int t = bid; t < T_COMB; t += nb) { ph_combine(p, t, tid, (float*)Bs); __syncthreads(); }
}

// ====================== fallback standalone kernels (R7 schedule) ======================
__global__ __launch_bounds__(256) void k_prep(MegaP p) {
    __shared__ float shf[32 * 33];
    ph_prep(p, blockIdx.x, threadIdx.x, shf);
}
__global__ __launch_bounds__(256) void k_wfold(MegaP p) {
    __shared__ _Float16 As[128 * 32]; __shared__ _Float16 Bs[128 * 32];
    ph_wfold(p, blockIdx.x, threadIdx.x, As, Bs);
}
__global__ __launch_bounds__(256) void k_wfoldsum(MegaP p) {
    const int i = blockIdx.x * 256 + threadIdx.x;
    if (i < ML * INn / 4) ph_wfoldsum(p, i);
}
__global__ __launch_bounds__(256) void k_upre(MegaP p) {
    __shared__ _Float16 As[128 * 32]; __shared__ _Float16 Bs[128 * 32];
    ph_upre(p, blockIdx.x, threadIdx.x, As, Bs);
}
__global__ __launch_bounds__(256) void k_convz(MegaP p) {
    ph_convz(p, blockIdx.x, threadIdx.x);
}
__global__ __launch_bounds__(256) void k_dtb(MegaP p) {
    __shared__ _Float16 As[128 * 32]; __shared__ _Float16 Bs[128 * 32];
    ph_dtb(p, blockIdx.x, threadIdx.x, As, Bs);
}
__global__ __launch_bounds__(256) void k_dtbsum(MegaP p) {
    ph_dtbsum(p, blockIdx.x, threadIdx.x);
}
__global__ __launch_bounds__(256) void k_delta(MegaP p) {
    __shared__ _Float16 As[128 * 32]; __shared__ _Float16 Bs[128 * 32];
    ph_delta(p, blockIdx.x, threadIdx.x, As, Bs);
}
__global__ __launch_bounds__(256) void k_scan(MegaP p) {
    ph_scan(p, blockIdx.x, threadIdx.x);
}
__global__ __launch_bounds__(256) void k_combine(MegaP p) {
    __shared__ float accs[16];
    ph_combine(p, blockIdx.x, threadIdx.x, accs);
}

} // namespace

extern "C" void kernel_launch(void* const* d_in, const int* in_sizes, int n_in,
                              void* d_out, int out_size, void* d_ws, size_t ws_size,
                              hipStream_t stream) {
    (void)in_sizes; (void)n_in; (void)out_size; (void)ws_size;
    const float* x       = (const float*)d_in[0];
    const float* W_emb   = (const float*)d_in[1];
    const float* b_emb   = (const float*)d_in[2];
    const float* in_proj = (const float*)d_in[3];
    const float* conv_w  = (const float*)d_in[4];
    const float* conv_b  = (const float*)d_in[5];
    const float* x_proj  = (const float*)d_in[6];
    const float* dt_w    = (const float*)d_in[7];
    const float* dt_b    = (const float*)d_in[8];
    const float* A_log   = (const float*)d_in[9];
    const float* Dp      = (const float*)d_in[10];
    const float* out_w   = (const float*)d_in[11];
    const float* fc_w    = (const float*)d_in[12];
    const float* fc_b    = (const float*)d_in[13];
    float* out = (float*)d_out;
    char* w8 = (char*)d_ws;

    const size_t MB = 1ull << 20;
    _Float16* upreh    = (_Float16*)(w8);            // 16 MB [upre -> conv]
    _Float16* uh       = (_Float16*)(w8 + 16 * MB);  // 16 MB [conv -> dtb/scan/combine]
    float*    wfoldP   = (float*)(w8 + 32 * MB);     // 16 MB [wfold -> wfoldsum]
    _Float16* deltah   = (_Float16*)(w8 + 32 * MB);  // aliases wfoldP [delta -> scan]
    float*    skp      = (float*)(w8 + 48 * MB);     // 10.5 MB [dtb -> dtbsum]
    float*    cS       = skp;                        // aliases skp [scan -> combine]
    _Float16* cH       = (_Float16*)(w8 + 50 * MB);  // 16.8 MB [scan -> combine]
    _Float16* dtBh     = (_Float16*)(w8 + 67 * MB);
    _Float16* xh       = (_Float16*)(w8 + 68 * MB);
    _Float16* W_embT_h = (_Float16*)(w8 + 70 * MB);
    _Float16* in_projh = (_Float16*)(w8 + 71 * MB);  // 8 MB
    _Float16* xp_h     = (_Float16*)(w8 + 79 * MB);
    _Float16* dt_wh    = (_Float16*)(w8 + 80 * MB);
    _Float16* Wfoldh   = (_Float16*)(w8 + 81 * MB);  // 2 MB
    float*    wp       = (float*)(w8 + 83 * MB);
    float*    badd     = (float*)(w8 + 84 * MB);
    float*    zlast    = badd + 4096;
    float*    Clast    = zlast + (size_t)Bn * DIn;

    MegaP p;
    p.x = x; p.b_emb = b_emb; p.in_proj = in_proj; p.conv_w = conv_w; p.conv_b = conv_b;
    p.x_proj = x_proj; p.dt_b = dt_b; p.A_log = A_log; p.Dp = Dp; p.out_w = out_w;
    p.fc_w = fc_w; p.fc_b = fc_b; p.W_emb = W_emb; p.dt_w = dt_w;
    p.out = out;
    p.xh = xh; p.iph = in_projh; p.dtwh = dt_wh; p.W_embT = W_embT_h; p.xp_h = xp_h;
    p.upreh = upreh; p.uh = uh; p.deltah = deltah; p.dtBh = dtBh; p.Wfoldh = Wfoldh;
    p.wfoldP = wfoldP; p.skp = skp; p.cS = cS; p.cH = cH;
    p.wp = wp; p.badd = badd; p.zlast = zlast; p.Clast = Clast;

    // ---- cooperative path: occupancy-clamped grid, checked launch ----
    bool coop_ok = false;
    int occ = 0;
    if (hipOccupancyMaxActiveBlocksPerMultiprocessor(&occ, mamba_mega, 256, 0) == hipSuccess
        && occ >= 1) {
        int nb = occ * 256;           // 256 CUs on MI355X
        if (nb > 512) nb = 512;
        void* args[] = { &p };
        coop_ok = (hipLaunchCooperativeKernel((void*)mamba_mega, dim3(nb), dim3(256),
                                              args, 0, stream) == hipSuccess);
    }
    if (!coop_ok) {
        // ---- fallback: proven 10-kernel schedule ----
        k_prep    <<<T_PREP,   256, 0, stream>>>(p);
        k_wfold   <<<T_WFOLD,  256, 0, stream>>>(p);
        k_wfoldsum<<<T_WFSUM,  256, 0, stream>>>(p);
        k_upre    <<<T_UPRE,   256, 0, stream>>>(p);
        k_convz   <<<T_CONVZ,  256, 0, stream>>>(p);
        k_dtb     <<<T_DTB,    256, 0, stream>>>(p);
        k_dtbsum  <<<T_DTBSUM, 256, 0, stream>>>(p);
        k_delta   <<<T_DELTA,  256, 0, stream>>>(p);
        k_scan    <<<T_SCAN,   256, 0, stream>>>(p);
        k_combine <<<T_COMB,   256, 0, stream>>>(p);
    }
}

// Round 10
// 152.314 us; speedup vs baseline: 2.8197x; 2.8197x over previous
//
#include <hip/hip_runtime.h>
#include <cstddef>
#include <cstdint>

namespace {

typedef _Float16 half8 __attribute__((ext_vector_type(8)));
typedef _Float16 half4 __attribute__((ext_vector_type(4)));
typedef float f32x4 __attribute__((ext_vector_type(4)));

constexpr int Bn   = 4;
constexpr int Ln   = 1024;
constexpr int INn  = 256;
constexpr int DMn  = 1024;
constexpr int DSn  = 16;
constexpr int DCn  = 4;
constexpr int DIn  = 2048;
constexpr int DTRn = 64;
constexpr int XPW  = DTRn + DSn;    // 80
constexpr int NCHUNK = 64;
constexpr int CHUNK  = Ln / NCHUNK; // 16
constexpr int WCH  = 32;
constexpr int ML   = Bn * Ln;       // 4096

__device__ __forceinline__ float silu_(float x) { return x / (1.f + __expf(-x)); }
__device__ __forceinline__ float softplus_(float x) {
    return fmaxf(x, 0.f) + __logf(1.f + __expf(-fabsf(x)));
}

// ================= prep (block-range dispatch), identical to R7 =================
__global__ __launch_bounds__(256)
void prep_mega(const float* __restrict__ x, _Float16* __restrict__ xh,
               const float* __restrict__ ip, _Float16* __restrict__ iph,
               const float* __restrict__ dtw, _Float16* __restrict__ dtwh,
               const float* __restrict__ W_emb, _Float16* __restrict__ W_embT,
               const float* __restrict__ x_proj, _Float16* __restrict__ xp_h,
               const float* __restrict__ fc_w, const float* __restrict__ out_w,
               float* __restrict__ wp,
               const float* __restrict__ b_emb, float* __restrict__ badd,
               const float* __restrict__ fc_b, float* __restrict__ out) {
    __shared__ float tile[32][33];
    const int bid = blockIdx.x, tid = threadIdx.x;
    if (bid < 4096) {
        const int n = bid;
        const float4 v = ((const float4*)ip)[n * 256 + tid];
        ((half4*)iph)[n * 256 + tid] =
            half4{(_Float16)v.x, (_Float16)v.y, (_Float16)v.z, (_Float16)v.w};
        const float4 bv = ((const float4*)b_emb)[tid];
        float s = v.x * bv.x + v.y * bv.y + v.z * bv.z + v.w * bv.w;
        for (int off = 32; off > 0; off >>= 1) s += __shfl_down(s, off);
        if ((tid & 63) == 0) tile[0][tid >> 6] = s;
        __syncthreads();
        if (tid == 0) badd[n] = tile[0][0] + tile[0][1] + tile[0][2] + tile[0][3];
    } else if (bid < 5248) {
        const float* in; _Float16* outp; int i;
        if (bid < 5120) { in = x;   outp = xh;   i = (bid - 4096) * 256 + tid; }
        else            { in = dtw; outp = dtwh; i = (bid - 5120) * 256 + tid; }
        const float4 v = ((const float4*)in)[i];
        ((half4*)outp)[i] = half4{(_Float16)v.x, (_Float16)v.y, (_Float16)v.z, (_Float16)v.w};
    } else if (bid < 5504) {
        const int bx = bid - 5248;
        const int m0 = (bx & 31) * 32, c0 = (bx >> 5) * 32;
        const int lc = tid & 31, lr = tid >> 5;
        #pragma unroll
        for (int ph = 0; ph < 4; ++ph)
            tile[lr + ph * 8][lc] = W_emb[(size_t)(m0 + lr + ph * 8) * INn + c0 + lc];
        __syncthreads();
        #pragma unroll
        for (int ph = 0; ph < 4; ++ph)
            W_embT[(size_t)(c0 + lr + ph * 8) * DMn + m0 + lc] = (_Float16)tile[lc][lr + ph * 8];
    } else if (bid < 5760) {
        const int i = (bid - 5504) * 256 + tid;
        const int r = i >> 9;
        const int c4 = i & 511;
        half4 h;
        if (r < XPW) {
            const float4 v = ((const float4*)(x_proj + (size_t)r * DIn))[c4];
            h = half4{(_Float16)v.x, (_Float16)v.y, (_Float16)v.z, (_Float16)v.w};
        } else {
            h = half4{(_Float16)0.f, (_Float16)0.f, (_Float16)0.f, (_Float16)0.f};
        }
        ((half4*)(xp_h + (size_t)r * DIn))[c4] = h;
    } else if (bid < 6016) {
        const int bx = bid - 5760;
        const int d = (bx & 7) * 256 + tid;
        const int c = bx >> 3;
        const int mstep = DMn / WCH;
        float s = 0.f;
        for (int m = c * mstep; m < (c + 1) * mstep; ++m)
            s += fc_w[m] * out_w[(size_t)m * DIn + d];
        wp[(size_t)c * DIn + d] = s;
    } else {
        if (tid < Bn) out[tid] = fc_b[0];
    }
}

// ---------------- generic split-K MFMA GEMM -> fp32 partials (proven) ----------------
__global__ __launch_bounds__(256)
void skgemm2(const _Float16* __restrict__ A, int lda,
             const _Float16* __restrict__ Bw, int ldb,
             float* __restrict__ P, int N, int Kc) {
    __shared__ _Float16 As[128 * 32];
    __shared__ _Float16 Bs[128 * 32];
    const int tid  = threadIdx.x;
    const int lane = tid & 63, wid = tid >> 6;
    const int wm = wid >> 1, wn = wid & 1;
    const int sk = blockIdx.x;
    const int m0 = blockIdx.y * 128;
    const int n0 = blockIdx.z * 128;
    const int M  = gridDim.y * 128;

    f32x4 acc[4][4] = {};
    const int kbeg = sk * Kc;
    for (int k0 = kbeg; k0 < kbeg + Kc; k0 += 32) {
        #pragma unroll
        for (int i = 0; i < 2; ++i) {
            const int off = tid * 16 + i * 4096;
            const int row = off >> 6;
            const int ch  = (off & 63) >> 1;
            __builtin_amdgcn_global_load_lds(
                (const __attribute__((address_space(1))) void*)(A + (size_t)(m0 + row) * lda + k0 + ch),
                (__attribute__((address_space(3))) void*)(&As[off >> 1]), 16, 0, 0);
            __builtin_amdgcn_global_load_lds(
                (const __attribute__((address_space(1))) void*)(Bw + (size_t)(n0 + row) * ldb + k0 + ch),
                (__attribute__((address_space(3))) void*)(&Bs[off >> 1]), 16, 0, 0);
        }
        __syncthreads();
        const int ar = lane & 15;
        const int kq = (lane >> 4) * 8;
        half8 af[4], bf[4];
        #pragma unroll
        for (int i = 0; i < 4; ++i)
            af[i] = *(const half8*)&As[(wm * 64 + i * 16 + ar) * 32 + kq];
        #pragma unroll
        for (int j = 0; j < 4; ++j)
            bf[j] = *(const half8*)&Bs[(wn * 64 + j * 16 + ar) * 32 + kq];
        #pragma unroll
        for (int i = 0; i < 4; ++i)
            #pragma unroll
            for (int j = 0; j < 4; ++j)
                acc[i][j] = __builtin_amdgcn_mfma_f32_16x16x32_f16(af[i], bf[j], acc[i][j], 0, 0, 0);
        __syncthreads();
    }
    const int cr = (lane >> 4) * 4;
    const int cn = lane & 15;
    #pragma unroll
    for (int i = 0; i < 4; ++i)
        #pragma unroll
        for (int j = 0; j < 4; ++j) {
            const int n = n0 + wn * 64 + j * 16 + cn;
            if (n < N) {
                #pragma unroll
                for (int r = 0; r < 4; ++r) {
                    const int m = m0 + wm * 64 + i * 16 + cr + r;
                    P[((size_t)sk * M + m) * N + n] = acc[i][j][r];
                }
            }
        }
}

// sum split-K partials -> fp16 (used for Wfold)
__global__ __launch_bounds__(256)
void skcomb(const float* __restrict__ P, _Float16* __restrict__ out, int total, int nsk) {
    const int i = blockIdx.x * 256 + threadIdx.x;
    if (i >= total) return;
    float s = 0.f;
    for (int k = 0; k < nsk; ++k) s += P[(size_t)k * total + i];
    out[i] = (_Float16)s;
}

// ---------------- MFMA fp16 GEMM (upre: fp16 + bias epilogue, proven) ----------
template<int ACT, bool HAS_BIAS>
__global__ __launch_bounds__(256)
void hgemm(const _Float16* __restrict__ A, int lda,
           const _Float16* __restrict__ Bw, int ldb,
           const float* __restrict__ bias,
           _Float16* __restrict__ Ch, int ldc,
           int N, int K) {
    __shared__ _Float16 As[128 * 32];
    __shared__ _Float16 Bs[128 * 32];
    const int tid  = threadIdx.x;
    const int lane = tid & 63, wid = tid >> 6;
    const int wm = wid >> 1, wn = wid & 1;
    const int m0 = blockIdx.y * 128, n0 = blockIdx.x * 128;

    f32x4 acc[4][4] = {};
    for (int k0 = 0; k0 < K; k0 += 32) {
        #pragma unroll
        for (int i = 0; i < 2; ++i) {
            const int off = tid * 16 + i * 4096;
            const int row = off >> 6;
            const int ch  = (off & 63) >> 1;
            __builtin_amdgcn_global_load_lds(
                (const __attribute__((address_space(1))) void*)(A + (size_t)(m0 + row) * lda + k0 + ch),
                (__attribute__((address_space(3))) void*)(&As[off >> 1]), 16, 0, 0);
            __builtin_amdgcn_global_load_lds(
                (const __attribute__((address_space(1))) void*)(Bw + (size_t)(n0 + row) * ldb + k0 + ch),
                (__attribute__((address_space(3))) void*)(&Bs[off >> 1]), 16, 0, 0);
        }
        __syncthreads();
        const int ar = lane & 15;
        const int kq = (lane >> 4) * 8;
        half8 af[4], bf[4];
        #pragma unroll
        for (int i = 0; i < 4; ++i)
            af[i] = *(const half8*)&As[(wm * 64 + i * 16 + ar) * 32 + kq];
        #pragma unroll
        for (int j = 0; j < 4; ++j)
            bf[j] = *(const half8*)&Bs[(wn * 64 + j * 16 + ar) * 32 + kq];
        #pragma unroll
        for (int i = 0; i < 4; ++i)
            #pragma unroll
            for (int j = 0; j < 4; ++j)
                acc[i][j] = __builtin_amdgcn_mfma_f32_16x16x32_f16(af[i], bf[j], acc[i][j], 0, 0, 0);
        __syncthreads();
    }
    const int cr = (lane >> 4) * 4;
    const int cn = lane & 15;
    #pragma unroll
    for (int i = 0; i < 4; ++i)
        #pragma unroll
        for (int j = 0; j < 4; ++j) {
            const int n = n0 + wn * 64 + j * 16 + cn;
            if (n < N) {
                #pragma unroll
                for (int r = 0; r < 4; ++r) {
                    const int m = m0 + wm * 64 + i * 16 + cr + r;
                    float v = acc[i][j][r];
                    if (HAS_BIAS) v += bias[n];
                    if (ACT == 1) v = softplus_(v);
                    Ch[(size_t)m * ldc + n] = (_Float16)v;
                }
            }
        }
}

// ------- conv+silu (blocks [0,1024)) + z_last fold GEMV (blocks [1024,1056)) -------
__global__ __launch_bounds__(256)
void conv_zlast(const _Float16* __restrict__ upre, const float* __restrict__ cw,
                const float* __restrict__ cb, _Float16* __restrict__ uh,
                const float* __restrict__ x, const _Float16* __restrict__ Wfh,
                const float* __restrict__ badd, float* __restrict__ zlast) {
    const int tid = threadIdx.x;
    const int bid = blockIdx.x;
    if (bid < 1024) {
        const int b  = bid >> 8;
        const int t0 = (bid & 255) * 4;
        const int d0 = tid * 8;
        const size_t rowbase = ((size_t)b * Ln + t0) * DIn + d0;
        half8 hzero;
        #pragma unroll
        for (int q = 0; q < 8; ++q) hzero[q] = (_Float16)0.f;
        half8 rows[7];
        if (t0 >= 3) {
            #pragma unroll
            for (int r = 0; r < 7; ++r)
                rows[r] = *(const half8*)(upre + rowbase + (ptrdiff_t)(r - 3) * DIn);
        } else {
            #pragma unroll
            for (int r = 0; r < 7; ++r) {
                const int t = t0 - 3 + r;
                rows[r] = (t >= 0) ? *(const half8*)(upre + rowbase + (ptrdiff_t)(r - 3) * DIn) : hzero;
            }
        }
        f32x4 cwq[8];
        float cbv[8];
        #pragma unroll
        for (int q = 0; q < 8; ++q) {
            cwq[q] = *(const f32x4*)(cw + (size_t)(d0 + q) * DCn);
            cbv[q] = cb[d0 + q];
        }
        #pragma unroll
        for (int s = 0; s < 4; ++s) {
            half8 o;
            #pragma unroll
            for (int q = 0; q < 8; ++q) {
                float acc = cbv[q];
                #pragma unroll
                for (int j = 0; j < DCn; ++j) acc += (float)rows[s + j][q] * cwq[q][j];
                o[q] = (_Float16)silu_(acc);
            }
            *(half8*)(uh + rowbase + (size_t)s * DIn) = o;
        }
    } else {
        const int t = (bid - 1024) * 256 + tid;
        const int j = t & (DIn - 1), b = t >> 11;
        const float4* x4 = (const float4*)(x + ((size_t)b * Ln + (Ln - 1)) * INn);
        const half4* w4 = (const half4*)(Wfh + (size_t)(DIn + j) * INn);
        float s = 0.f;
        #pragma unroll 8
        for (int q = 0; q < 64; ++q) {
            const float4 xv = x4[q];
            const half4 wv = w4[q];
            s += (float)wv[0] * xv.x + (float)wv[1] * xv.y
               + (float)wv[2] * xv.z + (float)wv[3] * xv.w;
        }
        zlast[(size_t)b * DIn + j] = s + badd[DIn + j];
    }
}

// ======== delta_fused: dtB partial-sum (A in LDS) + dtBh write + delta GEMM + clast ========
// blocks [0,128): (mt, ng) — sum skp into fp16 A-panels, ng==0 writes dtBh row,
//   then 4 n-tiles of K=64 MFMA with dtwh B-tiles + softplus -> deltah
// blocks [128,144): clast
__global__ __launch_bounds__(256)
void delta_fused(const float* __restrict__ skp, const _Float16* __restrict__ dtwh,
                 const float* __restrict__ dt_b, _Float16* __restrict__ dtBh,
                 _Float16* __restrict__ deltah,
                 const _Float16* __restrict__ uh, const float* __restrict__ x_proj,
                 float* __restrict__ Clast) {
    const int tid = threadIdx.x;
    const int bid = blockIdx.x;
    if (bid >= 128) {
        const int wave = tid >> 6, lane = tid & 63;
        const int task = (bid - 128) * 4 + wave;   // 64 tasks
        const int s_idx = task & 15, b = task >> 4;
        const _Float16* ur = uh + ((size_t)b * Ln + (Ln - 1)) * DIn;
        const float* w = x_proj + (size_t)(XPW + s_idx) * DIn;
        float s = 0.f;
        for (int k = lane; k < DIn; k += 64) s += (float)ur[k] * w[k];
        for (int off = 32; off > 0; off >>= 1) s += __shfl_down(s, off);
        if (lane == 0) Clast[b * DSn + s_idx] = s;
        return;
    }
    __shared__ _Float16 As[2 * 128 * 32];   // 2 K-panels of [128][32]
    __shared__ _Float16 Bs[2 * 128 * 32];
    const int mt = bid >> 2, ng = bid & 3;
    const int m0 = mt * 128;

    // ---- A: sum 8 fp32 partials for rows m0..+127, cols 0..79 ----
    {
        const int r = tid >> 1;
        const int c0 = (tid & 1) * 40;
        float4 s4[10];
        #pragma unroll
        for (int q = 0; q < 10; ++q) s4[q] = float4{0.f, 0.f, 0.f, 0.f};
        #pragma unroll
        for (int sk = 0; sk < 8; ++sk) {
            const float4* src = (const float4*)(skp + (size_t)sk * (ML * XPW)
                                                + (size_t)(m0 + r) * XPW + c0);
            #pragma unroll
            for (int q = 0; q < 10; ++q) {
                const float4 v = src[q];
                s4[q].x += v.x; s4[q].y += v.y; s4[q].z += v.z; s4[q].w += v.w;
            }
        }
        #pragma unroll
        for (int q = 0; q < 10; ++q) {
            const int c = c0 + q * 4;
            if (c < 64) {   // panel layout: As[(c>>5)*4096 + r*32 + (c&31)]
                const int base = (c >> 5) * 4096 + r * 32 + (c & 31);
                As[base + 0] = (_Float16)s4[q].x;
                As[base + 1] = (_Float16)s4[q].y;
                As[base + 2] = (_Float16)s4[q].z;
                As[base + 3] = (_Float16)s4[q].w;
            }
        }
        if (ng == 0) {
            half4* dst = (half4*)(dtBh + (size_t)(m0 + r) * XPW + c0);
            #pragma unroll
            for (int q = 0; q < 10; ++q)
                dst[q] = half4{(_Float16)s4[q].x, (_Float16)s4[q].y,
                               (_Float16)s4[q].z, (_Float16)s4[q].w};
        }
    }
    __syncthreads();

    // ---- 4 n-tiles: stage dtwh B-tile, MFMA K=64, softplus epilogue ----
    const int lane = tid & 63, wid = tid >> 6;
    const int wm = wid >> 1, wn = wid & 1;
    const int ar = lane & 15;
    const int kq = (lane >> 4) * 8;
    const int cr = (lane >> 4) * 4;
    const int cn = lane & 15;
    for (int j = 0; j < 4; ++j) {
        const int n0 = (ng * 4 + j) * 128;
        #pragma unroll
        for (int ro = 0; ro < 4; ++ro) {
            const int e0 = (ro * 256 + tid) * 8;   // half index in Bs
            const int ks = e0 >> 12;
            const int rem = e0 & 4095;
            const int rr = rem >> 5;
            const int cc = rem & 31;
            __builtin_amdgcn_global_load_lds(
                (const __attribute__((address_space(1))) void*)(dtwh + (size_t)(n0 + rr) * DTRn + ks * 32 + cc),
                (__attribute__((address_space(3))) void*)(Bs + e0), 16, 0, 0);
        }
        __syncthreads();
        f32x4 acc[4][4] = {};
        #pragma unroll
        for (int ks = 0; ks < 2; ++ks) {
            half8 af[4], bf[4];
            #pragma unroll
            for (int i = 0; i < 4; ++i)
                af[i] = *(const half8*)(As + ks * 4096 + (wm * 64 + i * 16 + ar) * 32 + kq);
            #pragma unroll
            for (int jj = 0; jj < 4; ++jj)
                bf[jj] = *(const half8*)(Bs + ks * 4096 + (wn * 64 + jj * 16 + ar) * 32 + kq);
            #pragma unroll
            for (int i = 0; i < 4; ++i)
                #pragma unroll
                for (int jj = 0; jj < 4; ++jj)
                    acc[i][jj] = __builtin_amdgcn_mfma_f32_16x16x32_f16(af[i], bf[jj], acc[i][jj], 0, 0, 0);
        }
        #pragma unroll
        for (int i = 0; i < 4; ++i)
            #pragma unroll
            for (int jj = 0; jj < 4; ++jj) {
                const int n = n0 + wn * 64 + jj * 16 + cn;
                #pragma unroll
                for (int r2 = 0; r2 < 4; ++r2) {
                    const int m = m0 + wm * 64 + i * 16 + cr + r2;
                    deltah[(size_t)m * DIn + n] = (_Float16)softplus_(acc[i][jj][r2] + dt_b[n]);
                }
            }
        __syncthreads();
    }
}

// ---------------- chunked scan (powers-trick, proven) ----------------
__global__ __launch_bounds__(256)
void scan_chunk_kernel(const _Float16* __restrict__ delta, const _Float16* __restrict__ u,
                       const _Float16* __restrict__ dtBh, const float* __restrict__ A_log,
                       float* __restrict__ cS, _Float16* __restrict__ cH) {
    const int d = blockIdx.x * 256 + threadIdx.x;
    const int c = blockIdx.y, b = blockIdx.z;
    float A[DSn], h[DSn];
    const float4* al = (const float4*)(A_log + (size_t)d * DSn);
    #pragma unroll
    for (int q = 0; q < 4; ++q) {
        const float4 v = al[q];
        A[q * 4 + 0] = -__expf(v.x); A[q * 4 + 1] = -__expf(v.y);
        A[q * 4 + 2] = -__expf(v.z); A[q * 4 + 3] = -__expf(v.w);
        h[q * 4 + 0] = 0.f; h[q * 4 + 1] = 0.f; h[q * 4 + 2] = 0.f; h[q * 4 + 3] = 0.f;
    }
    const float A0 = A[0];
    bool structured = true;
    #pragma unroll
    for (int s = 1; s < DSn; ++s)
        structured = structured && (fabsf(A[s] - (float)(s + 1) * A0) <= 1e-4f * (s + 1));
    float Ssum = 0.f;
    const size_t base = ((size_t)b * Ln + (size_t)c * CHUNK) * DIn + d;
    const _Float16* Bp = dtBh + ((size_t)b * Ln + (size_t)c * CHUNK) * XPW + DTRn;
    if (structured) {
        #pragma unroll 4
        for (int tt = 0; tt < CHUNK; ++tt) {
            const float dl = (float)delta[base + (size_t)tt * DIn];
            const float uu = (float)u[base + (size_t)tt * DIn];
            const float du = dl * uu;
            Ssum += dl;
            const half8 bv0 = *(const half8*)(Bp + tt * XPW);
            const half8 bv1 = *(const half8*)(Bp + tt * XPW + 8);
            float Bv[DSn];
            #pragma unroll
            for (int q = 0; q < 8; ++q) { Bv[q] = (float)bv0[q]; Bv[8 + q] = (float)bv1[q]; }
            const float e1 = __expf(dl * A0);
            const float e2 = e1 * e1, e4 = e2 * e2, e8 = e4 * e4;
            float E[DSn];
            E[0] = e1;      E[1] = e2;      E[2] = e2 * e1;  E[3] = e4;
            E[4] = e4 * e1; E[5] = e4 * e2; E[6] = E[5] * e1; E[7] = e8;
            E[8] = e8 * e1; E[9] = e8 * e2; E[10] = E[9] * e1; E[11] = e8 * e4;
            E[12] = E[11] * e1; E[13] = E[11] * e2; E[14] = E[13] * e1; E[15] = e8 * e8;
            #pragma unroll
            for (int s = 0; s < DSn; ++s) h[s] = E[s] * h[s] + du * Bv[s];
        }
    } else {
        #pragma unroll 4
        for (int tt = 0; tt < CHUNK; ++tt) {
            const float dl = (float)delta[base + (size_t)tt * DIn];
            const float uu = (float)u[base + (size_t)tt * DIn];
            const float du = dl * uu;
            Ssum += dl;
            const half8 bv0 = *(const half8*)(Bp + tt * XPW);
            const half8 bv1 = *(const half8*)(Bp + tt * XPW + 8);
            float Bv[DSn];
            #pragma unroll
            for (int q = 0; q < 8; ++q) { Bv[q] = (float)bv0[q]; Bv[8 + q] = (float)bv1[q]; }
            #pragma unroll
            for (int s = 0; s < DSn; ++s) h[s] = __expf(dl * A[s]) * h[s] + du * Bv[s];
        }
    }
    const size_t cidx = ((size_t)b * NCHUNK + c) * DIn + d;
    cS[cidx] = Ssum;
    half8 o0, o1;
    #pragma unroll
    for (int q = 0; q < 8; ++q) { o0[q] = (_Float16)h[q]; o1[q] = (_Float16)h[8 + q]; }
    *(half8*)(cH + cidx * DSn) = o0;
    *(half8*)(cH + cidx * DSn + 8) = o1;
}

// ------- combine: fold chunks + gate + weff dot + atomic out (proven) -------
__global__ __launch_bounds__(256)
void combine_v3(const float* __restrict__ cS, const _Float16* __restrict__ cH,
                const float* __restrict__ A_log, const float* __restrict__ Clast,
                const float* __restrict__ Dp, const _Float16* __restrict__ u,
                const float* __restrict__ zlast, const float* __restrict__ wp,
                float* __restrict__ out) {
    __shared__ float acc[16];
    const int tid = threadIdx.x;
    const int s = tid & 15;
    const int d = blockIdx.x * 16 + (tid >> 4);
    const int b = blockIdx.y;
    const float A = -__expf(A_log[(size_t)d * DSn + s]);
    float h = 0.f;
    const size_t cb0 = (size_t)b * NCHUNK;
    for (int c = 0; c < NCHUNK; ++c) {
        const size_t cidx = (cb0 + c) * DIn + d;
        h = __expf(A * cS[cidx]) * h + (float)cH[cidx * DSn + s];
    }
    float y = h * Clast[b * DSn + s];
    y += __shfl_xor(y, 1);
    y += __shfl_xor(y, 2);
    y += __shfl_xor(y, 4);
    y += __shfl_xor(y, 8);
    if (s == 0) {
        const float ul = (float)u[((size_t)b * Ln + (Ln - 1)) * DIn + d];
        float yy = y + Dp[d] * ul;
        yy *= silu_(zlast[(size_t)b * DIn + d]);
        float w = 0.f;
        #pragma unroll
        for (int c = 0; c < WCH; ++c) w += wp[(size_t)c * DIn + d];
        acc[tid >> 4] = yy * w;
    }
    __syncthreads();
    if (tid == 0) {
        float t = 0.f;
        #pragma unroll
        for (int i = 0; i < 16; ++i) t += acc[i];
        atomicAdd(&out[b], t);
    }
}

} // namespace

extern "C" void kernel_launch(void* const* d_in, const int* in_sizes, int n_in,
                              void* d_out, int out_size, void* d_ws, size_t ws_size,
                              hipStream_t stream) {
    (void)in_sizes; (void)n_in; (void)out_size; (void)ws_size;
    const float* x       = (const float*)d_in[0];
    const float* W_emb   = (const float*)d_in[1];
    const float* b_emb   = (const float*)d_in[2];
    const float* in_proj = (const float*)d_in[3];
    const float* conv_w  = (const float*)d_in[4];
    const float* conv_b  = (const float*)d_in[5];
    const float* x_proj  = (const float*)d_in[6];
    const float* dt_w    = (const float*)d_in[7];
    const float* dt_b    = (const float*)d_in[8];
    const float* A_log   = (const float*)d_in[9];
    const float* Dp      = (const float*)d_in[10];
    const float* out_w   = (const float*)d_in[11];
    const float* fc_w    = (const float*)d_in[12];
    const float* fc_b    = (const float*)d_in[13];
    float* out = (float*)d_out;
    char* w8 = (char*)d_ws;

    const size_t MB = 1ull << 20;
    _Float16* upreh    = (_Float16*)(w8);            // 16 MB [upre -> conv]
    _Float16* uh       = (_Float16*)(w8 + 16 * MB);  // 16 MB [conv -> dtb/scan/combine]
    float*    wfoldP   = (float*)(w8 + 32 * MB);     // 16 MB [wfold -> wfoldsum]
    _Float16* deltah   = (_Float16*)(w8 + 32 * MB);  // aliases wfoldP [delta -> scan]
    float*    skp      = (float*)(w8 + 48 * MB);     // 10.5 MB [dtb -> delta_fused]
    float*    cS       = skp;                        // aliases skp [scan -> combine]
    _Float16* cH       = (_Float16*)(w8 + 50 * MB);  // 16.8 MB [scan -> combine]
    _Float16* dtBh     = (_Float16*)(w8 + 67 * MB);
    _Float16* xh       = (_Float16*)(w8 + 68 * MB);
    _Float16* W_embT_h = (_Float16*)(w8 + 70 * MB);
    _Float16* in_projh = (_Float16*)(w8 + 71 * MB);  // 8 MB
    _Float16* xp_h     = (_Float16*)(w8 + 79 * MB);
    _Float16* dt_wh    = (_Float16*)(w8 + 80 * MB);
    _Float16* Wfoldh   = (_Float16*)(w8 + 81 * MB);  // 2 MB
    float*    wp       = (float*)(w8 + 83 * MB);
    float*    badd     = (float*)(w8 + 84 * MB);
    float*    zlast    = badd + 4096;
    float*    Clast    = zlast + (size_t)Bn * DIn;

    // 1. prep: conversions + weff + badd + out init
    prep_mega<<<6017, 256, 0, stream>>>(x, xh, in_proj, in_projh, dt_w, dt_wh,
                                        W_emb, W_embT_h, x_proj, xp_h,
                                        fc_w, out_w, wp, b_emb, badd, fc_b, out);
    // 2. Wfold = in_proj @ W_emb (split-K 4)
    skgemm2<<<dim3(4, ML / 128, 2), 256, 0, stream>>>(
        in_projh, DMn, W_embT_h, DMn, wfoldP, INn, 256);
    // 3. Wfold partial sum -> fp16
    skcomb<<<(ML * INn + 255) / 256, 256, 0, stream>>>(wfoldP, Wfoldh, ML * INn, 4);
    // 4. upre = fp16(x @ Wfold_u^T + badd_u), K=256
    hgemm<0, true><<<dim3(DIn / 128, ML / 128), 256, 0, stream>>>(
        xh, INn, Wfoldh, INn, badd, upreh, DIn, DIn, INn);
    // 5. uh = silu(conv(upre)+cb); z_last fold GEMV
    conv_zlast<<<1056, 256, 0, stream>>>(upreh, conv_w, conv_b, uh, x, Wfoldh, badd, zlast);
    // 6. dtB partials = uh @ xp^T (split-K 8)
    skgemm2<<<dim3(8, ML / 128, 1), 256, 0, stream>>>(uh, DIn, xp_h, DIn, skp, XPW, 256);
    // 7. fused: dtB sum -> dtBh + delta GEMM (K=64, softplus) + C_last
    delta_fused<<<144, 256, 0, stream>>>(skp, dt_wh, dt_b, dtBh, deltah, uh, x_proj, Clast);
    // 8. chunked scan (cS aliases skp, dead now)
    scan_chunk_kernel<<<dim3(DIn / 256, NCHUNK, Bn), 256, 0, stream>>>(
        deltah, uh, dtBh, A_log, cS, cH);
    // 9. combine + gate + weff dot + atomic out
    combine_v3<<<dim3(DIn / 16, Bn), 256, 0, stream>>>(
        cS, cH, A_log, Clast, Dp, uh, zlast, wp, out);
}

// Round 11
// 142.995 us; speedup vs baseline: 3.0035x; 1.0652x over previous
//
#include <hip/hip_runtime.h>
#include <cstddef>
#include <cstdint>

namespace {

typedef _Float16 half8 __attribute__((ext_vector_type(8)));
typedef _Float16 half4 __attribute__((ext_vector_type(4)));
typedef float f32x4 __attribute__((ext_vector_type(4)));

constexpr int Bn   = 4;
constexpr int Ln   = 1024;
constexpr int INn  = 256;
constexpr int DMn  = 1024;
constexpr int DSn  = 16;
constexpr int DCn  = 4;
constexpr int DIn  = 2048;
constexpr int DTRn = 64;
constexpr int XPW  = DTRn + DSn;    // 80
constexpr int NCHUNK = 64;
constexpr int CHUNK  = Ln / NCHUNK; // 16
constexpr int WCH  = 32;
constexpr int ML   = Bn * Ln;       // 4096

__device__ __forceinline__ float silu_(float x) { return x / (1.f + __expf(-x)); }
__device__ __forceinline__ float softplus_(float x) {
    return fmaxf(x, 0.f) + __logf(1.f + __expf(-fabsf(x)));
}

// ================= prep (block-range dispatch) =================
__global__ __launch_bounds__(256)
void prep_mega(const float* __restrict__ x, _Float16* __restrict__ xh,
               const float* __restrict__ ip, _Float16* __restrict__ iph,
               const float* __restrict__ dtw, _Float16* __restrict__ dtwh,
               const float* __restrict__ W_emb, _Float16* __restrict__ W_embT,
               const float* __restrict__ x_proj, _Float16* __restrict__ xp_h,
               const float* __restrict__ fc_w, const float* __restrict__ out_w,
               float* __restrict__ wp,
               const float* __restrict__ b_emb, float* __restrict__ badd,
               const float* __restrict__ fc_b, float* __restrict__ out,
               int* __restrict__ cnt) {
    __shared__ float tile[32][33];
    const int bid = blockIdx.x, tid = threadIdx.x;
    if (bid < 4096) {
        const int n = bid;
        const float4 v = ((const float4*)ip)[n * 256 + tid];
        ((half4*)iph)[n * 256 + tid] =
            half4{(_Float16)v.x, (_Float16)v.y, (_Float16)v.z, (_Float16)v.w};
        const float4 bv = ((const float4*)b_emb)[tid];
        float s = v.x * bv.x + v.y * bv.y + v.z * bv.z + v.w * bv.w;
        for (int off = 32; off > 0; off >>= 1) s += __shfl_down(s, off);
        if ((tid & 63) == 0) tile[0][tid >> 6] = s;
        __syncthreads();
        if (tid == 0) badd[n] = tile[0][0] + tile[0][1] + tile[0][2] + tile[0][3];
    } else if (bid < 5248) {
        const float* in; _Float16* outp; int i;
        if (bid < 5120) { in = x;   outp = xh;   i = (bid - 4096) * 256 + tid; }
        else            { in = dtw; outp = dtwh; i = (bid - 5120) * 256 + tid; }
        const float4 v = ((const float4*)in)[i];
        ((half4*)outp)[i] = half4{(_Float16)v.x, (_Float16)v.y, (_Float16)v.z, (_Float16)v.w};
    } else if (bid < 5504) {
        const int bx = bid - 5248;
        const int m0 = (bx & 31) * 32, c0 = (bx >> 5) * 32;
        const int lc = tid & 31, lr = tid >> 5;
        #pragma unroll
        for (int ph = 0; ph < 4; ++ph)
            tile[lr + ph * 8][lc] = W_emb[(size_t)(m0 + lr + ph * 8) * INn + c0 + lc];
        __syncthreads();
        #pragma unroll
        for (int ph = 0; ph < 4; ++ph)
            W_embT[(size_t)(c0 + lr + ph * 8) * DMn + m0 + lc] = (_Float16)tile[lc][lr + ph * 8];
    } else if (bid < 5760) {
        const int i = (bid - 5504) * 256 + tid;
        const int r = i >> 9;
        const int c4 = i & 511;
        half4 h;
        if (r < XPW) {
            const float4 v = ((const float4*)(x_proj + (size_t)r * DIn))[c4];
            h = half4{(_Float16)v.x, (_Float16)v.y, (_Float16)v.z, (_Float16)v.w};
        } else {
            h = half4{(_Float16)0.f, (_Float16)0.f, (_Float16)0.f, (_Float16)0.f};
        }
        ((half4*)(xp_h + (size_t)r * DIn))[c4] = h;
    } else if (bid < 6016) {
        const int bx = bid - 5760;
        const int d = (bx & 7) * 256 + tid;
        const int c = bx >> 3;
        const int mstep = DMn / WCH;
        float s = 0.f;
        for (int m = c * mstep; m < (c + 1) * mstep; ++m)
            s += fc_w[m] * out_w[(size_t)m * DIn + d];
        wp[(size_t)c * DIn + d] = s;
    } else {
        if (tid < Bn) out[tid] = fc_b[0];
        if (tid >= 8 && tid < 8 + 96) cnt[tid - 8] = 0;   // wfold: 64, dtb: 32
    }
}

// ====== wfold_fused: split-K MFMA GEMM + last-block partial reduce -> fp16 ======
// grid (4, 32, 2): A=iph [4096][1024], B=W_embT [256][1024], Kc=256, N=256.
__global__ __launch_bounds__(256)
void wfold_fused(const _Float16* __restrict__ A, const _Float16* __restrict__ Bw,
                 float* __restrict__ P, _Float16* __restrict__ Wfoldh,
                 int* __restrict__ cnt) {
    __shared__ _Float16 As[128 * 32];
    __shared__ _Float16 Bs[128 * 32];
    __shared__ int lastflag;
    const int tid  = threadIdx.x;
    const int lane = tid & 63, wid = tid >> 6;
    const int wm = wid >> 1, wn = wid & 1;
    const int sk = blockIdx.x;
    const int m0 = blockIdx.y * 128;
    const int n0 = blockIdx.z * 128;
    const int tileId = blockIdx.y * 2 + blockIdx.z;

    f32x4 acc[4][4] = {};
    const int kbeg = sk * 256;
    for (int k0 = kbeg; k0 < kbeg + 256; k0 += 32) {
        #pragma unroll
        for (int i = 0; i < 2; ++i) {
            const int off = tid * 16 + i * 4096;
            const int row = off >> 6;
            const int ch  = (off & 63) >> 1;
            __builtin_amdgcn_global_load_lds(
                (const __attribute__((address_space(1))) void*)(A + (size_t)(m0 + row) * DMn + k0 + ch),
                (__attribute__((address_space(3))) void*)(&As[off >> 1]), 16, 0, 0);
            __builtin_amdgcn_global_load_lds(
                (const __attribute__((address_space(1))) void*)(Bw + (size_t)(n0 + row) * DMn + k0 + ch),
                (__attribute__((address_space(3))) void*)(&Bs[off >> 1]), 16, 0, 0);
        }
        __syncthreads();
        const int ar = lane & 15;
        const int kq = (lane >> 4) * 8;
        half8 af[4], bf[4];
        #pragma unroll
        for (int i = 0; i < 4; ++i)
            af[i] = *(const half8*)&As[(wm * 64 + i * 16 + ar) * 32 + kq];
        #pragma unroll
        for (int j = 0; j < 4; ++j)
            bf[j] = *(const half8*)&Bs[(wn * 64 + j * 16 + ar) * 32 + kq];
        #pragma unroll
        for (int i = 0; i < 4; ++i)
            #pragma unroll
            for (int j = 0; j < 4; ++j)
                acc[i][j] = __builtin_amdgcn_mfma_f32_16x16x32_f16(af[i], bf[j], acc[i][j], 0, 0, 0);
        __syncthreads();
    }
    const int cr = (lane >> 4) * 4;
    const int cn = lane & 15;
    #pragma unroll
    for (int i = 0; i < 4; ++i)
        #pragma unroll
        for (int j = 0; j < 4; ++j) {
            const int n = n0 + wn * 64 + j * 16 + cn;
            #pragma unroll
            for (int r = 0; r < 4; ++r) {
                const int m = m0 + wm * 64 + i * 16 + cr + r;
                P[((size_t)sk * ML + m) * INn + n] = acc[i][j][r];
            }
        }
    // ---- last-block reduce for this tile ----
    __syncthreads();
    if (tid == 0) {
        __threadfence();
        lastflag = (atomicAdd(&cnt[tileId], 1) == 3);
    }
    __syncthreads();
    if (!lastflag) return;
    __threadfence();
    // sum 4 partials over rows m0..+127, cols n0..+127 (row stride INn)
    for (int q = 0; q < 16; ++q) {
        const int i = q * 256 + tid;            // 4096 quads = 128 rows x 32 quads
        const int r = i >> 5, c4 = i & 31;
        const size_t base = (size_t)(m0 + r) * INn + n0 + c4 * 4;
        float4 s = *(const float4*)(P + base);
        #pragma unroll
        for (int k = 1; k < 4; ++k) {
            const float4 v = *(const float4*)(P + (size_t)k * ML * INn + base);
            s.x += v.x; s.y += v.y; s.z += v.z; s.w += v.w;
        }
        *(half4*)(Wfoldh + base) = half4{(_Float16)s.x, (_Float16)s.y, (_Float16)s.z, (_Float16)s.w};
    }
}

// ---------------- MFMA fp16 GEMM (upre: fp16 + bias epilogue, proven) ----------
__global__ __launch_bounds__(256)
void hgemm_upre(const _Float16* __restrict__ A, const _Float16* __restrict__ Bw,
                const float* __restrict__ bias, _Float16* __restrict__ Ch) {
    __shared__ _Float16 As[128 * 32];
    __shared__ _Float16 Bs[128 * 32];
    const int tid  = threadIdx.x;
    const int lane = tid & 63, wid = tid >> 6;
    const int wm = wid >> 1, wn = wid & 1;
    const int m0 = blockIdx.y * 128, n0 = blockIdx.x * 128;

    f32x4 acc[4][4] = {};
    for (int k0 = 0; k0 < INn; k0 += 32) {
        #pragma unroll
        for (int i = 0; i < 2; ++i) {
            const int off = tid * 16 + i * 4096;
            const int row = off >> 6;
            const int ch  = (off & 63) >> 1;
            __builtin_amdgcn_global_load_lds(
                (const __attribute__((address_space(1))) void*)(A + (size_t)(m0 + row) * INn + k0 + ch),
                (__attribute__((address_space(3))) void*)(&As[off >> 1]), 16, 0, 0);
            __builtin_amdgcn_global_load_lds(
                (const __attribute__((address_space(1))) void*)(Bw + (size_t)(n0 + row) * INn + k0 + ch),
                (__attribute__((address_space(3))) void*)(&Bs[off >> 1]), 16, 0, 0);
        }
        __syncthreads();
        const int ar = lane & 15;
        const int kq = (lane >> 4) * 8;
        half8 af[4], bf[4];
        #pragma unroll
        for (int i = 0; i < 4; ++i)
            af[i] = *(const half8*)&As[(wm * 64 + i * 16 + ar) * 32 + kq];
        #pragma unroll
        for (int j = 0; j < 4; ++j)
            bf[j] = *(const half8*)&Bs[(wn * 64 + j * 16 + ar) * 32 + kq];
        #pragma unroll
        for (int i = 0; i < 4; ++i)
            #pragma unroll
            for (int j = 0; j < 4; ++j)
                acc[i][j] = __builtin_amdgcn_mfma_f32_16x16x32_f16(af[i], bf[j], acc[i][j], 0, 0, 0);
        __syncthreads();
    }
    const int cr = (lane >> 4) * 4;
    const int cn = lane & 15;
    #pragma unroll
    for (int i = 0; i < 4; ++i)
        #pragma unroll
        for (int j = 0; j < 4; ++j) {
            const int n = n0 + wn * 64 + j * 16 + cn;
            #pragma unroll
            for (int r = 0; r < 4; ++r) {
                const int m = m0 + wm * 64 + i * 16 + cr + r;
                Ch[(size_t)m * DIn + n] = (_Float16)(acc[i][j][r] + bias[n]);
            }
        }
}

// ------- conv+silu (blocks [0,1024)) + z_last fold GEMV (blocks [1024,1056)) -------
__global__ __launch_bounds__(256)
void conv_zlast(const _Float16* __restrict__ upre, const float* __restrict__ cw,
                const float* __restrict__ cb, _Float16* __restrict__ uh,
                const float* __restrict__ x, const _Float16* __restrict__ Wfh,
                const float* __restrict__ badd, float* __restrict__ zlast) {
    const int tid = threadIdx.x;
    const int bid = blockIdx.x;
    if (bid < 1024) {
        const int b  = bid >> 8;
        const int t0 = (bid & 255) * 4;
        const int d0 = tid * 8;
        const size_t rowbase = ((size_t)b * Ln + t0) * DIn + d0;
        half8 hzero;
        #pragma unroll
        for (int q = 0; q < 8; ++q) hzero[q] = (_Float16)0.f;
        half8 rows[7];
        if (t0 >= 3) {
            #pragma unroll
            for (int r = 0; r < 7; ++r)
                rows[r] = *(const half8*)(upre + rowbase + (ptrdiff_t)(r - 3) * DIn);
        } else {
            #pragma unroll
            for (int r = 0; r < 7; ++r) {
                const int t = t0 - 3 + r;
                rows[r] = (t >= 0) ? *(const half8*)(upre + rowbase + (ptrdiff_t)(r - 3) * DIn) : hzero;
            }
        }
        f32x4 cwq[8];
        float cbv[8];
        #pragma unroll
        for (int q = 0; q < 8; ++q) {
            cwq[q] = *(const f32x4*)(cw + (size_t)(d0 + q) * DCn);
            cbv[q] = cb[d0 + q];
        }
        #pragma unroll
        for (int s = 0; s < 4; ++s) {
            half8 o;
            #pragma unroll
            for (int q = 0; q < 8; ++q) {
                float acc = cbv[q];
                #pragma unroll
                for (int j = 0; j < DCn; ++j) acc += (float)rows[s + j][q] * cwq[q][j];
                o[q] = (_Float16)silu_(acc);
            }
            *(half8*)(uh + rowbase + (size_t)s * DIn) = o;
        }
    } else {
        const int t = (bid - 1024) * 256 + tid;
        const int j = t & (DIn - 1), b = t >> 11;
        const float4* x4 = (const float4*)(x + ((size_t)b * Ln + (Ln - 1)) * INn);
        const half4* w4 = (const half4*)(Wfh + (size_t)(DIn + j) * INn);
        float s = 0.f;
        #pragma unroll 8
        for (int q = 0; q < 64; ++q) {
            const float4 xv = x4[q];
            const half4 wv = w4[q];
            s += (float)wv[0] * xv.x + (float)wv[1] * xv.y
               + (float)wv[2] * xv.z + (float)wv[3] * xv.w;
        }
        zlast[(size_t)b * DIn + j] = s + badd[DIn + j];
    }
}

// ====== dtb_fused: split-K MFMA GEMM (N=80) + last-block reduce -> fp16 dtBh ======
// grid (8, 32): A=uh [4096][2048], B=xp_h [128][2048] padded, Kc=256.
__global__ __launch_bounds__(256)
void dtb_fused(const _Float16* __restrict__ A, const _Float16* __restrict__ Bw,
               float* __restrict__ P, _Float16* __restrict__ dtBh,
               int* __restrict__ cnt) {
    __shared__ _Float16 As[128 * 32];
    __shared__ _Float16 Bs[128 * 32];
    __shared__ int lastflag;
    const int tid  = threadIdx.x;
    const int lane = tid & 63, wid = tid >> 6;
    const int wm = wid >> 1, wn = wid & 1;
    const int sk = blockIdx.x;
    const int m0 = blockIdx.y * 128;

    f32x4 acc[4][4] = {};
    const int kbeg = sk * 256;
    for (int k0 = kbeg; k0 < kbeg + 256; k0 += 32) {
        #pragma unroll
        for (int i = 0; i < 2; ++i) {
            const int off = tid * 16 + i * 4096;
            const int row = off >> 6;
            const int ch  = (off & 63) >> 1;
            __builtin_amdgcn_global_load_lds(
                (const __attribute__((address_space(1))) void*)(A + (size_t)(m0 + row) * DIn + k0 + ch),
                (__attribute__((address_space(3))) void*)(&As[off >> 1]), 16, 0, 0);
            __builtin_amdgcn_global_load_lds(
                (const __attribute__((address_space(1))) void*)(Bw + (size_t)row * DIn + k0 + ch),
                (__attribute__((address_space(3))) void*)(&Bs[off >> 1]), 16, 0, 0);
        }
        __syncthreads();
        const int ar = lane & 15;
        const int kq = (lane >> 4) * 8;
        half8 af[4], bf[4];
        #pragma unroll
        for (int i = 0; i < 4; ++i)
            af[i] = *(const half8*)&As[(wm * 64 + i * 16 + ar) * 32 + kq];
        #pragma unroll
        for (int j = 0; j < 4; ++j)
            bf[j] = *(const half8*)&Bs[(wn * 64 + j * 16 + ar) * 32 + kq];
        #pragma unroll
        for (int i = 0; i < 4; ++i)
            #pragma unroll
            for (int j = 0; j < 4; ++j)
                acc[i][j] = __builtin_amdgcn_mfma_f32_16x16x32_f16(af[i], bf[j], acc[i][j], 0, 0, 0);
        __syncthreads();
    }
    const int cr = (lane >> 4) * 4;
    const int cn = lane & 15;
    #pragma unroll
    for (int i = 0; i < 4; ++i)
        #pragma unroll
        for (int j = 0; j < 4; ++j) {
            const int n = wn * 64 + j * 16 + cn;
            if (n < XPW) {
                #pragma unroll
                for (int r = 0; r < 4; ++r) {
                    const int m = m0 + wm * 64 + i * 16 + cr + r;
                    P[((size_t)sk * ML + m) * XPW + n] = acc[i][j][r];
                }
            }
        }
    // ---- last-block reduce ----
    __syncthreads();
    if (tid == 0) {
        __threadfence();
        lastflag = (atomicAdd(&cnt[64 + blockIdx.y], 1) == 7);
    }
    __syncthreads();
    if (!lastflag) return;
    __threadfence();
    // 128 rows x 80 cols = 2560 quads; 10 quads/thread
    for (int q = 0; q < 10; ++q) {
        const int i = q * 256 + tid;
        const int r = i / 20, c4 = i % 20;
        const size_t base = (size_t)(m0 + r) * XPW + c4 * 4;
        float4 s = *(const float4*)(P + base);
        #pragma unroll
        for (int k = 1; k < 8; ++k) {
            const float4 v = *(const float4*)(P + (size_t)k * ML * XPW + base);
            s.x += v.x; s.y += v.y; s.z += v.z; s.w += v.w;
        }
        *(half4*)(dtBh + base) = half4{(_Float16)s.x, (_Float16)s.y, (_Float16)s.z, (_Float16)s.w};
    }
}

// ------- delta GEMM (K=64, softplus) + clast (blockIdx.x==16) -------
__global__ __launch_bounds__(256)
void delta_clast(const _Float16* __restrict__ A, const _Float16* __restrict__ Bw,
                 const float* __restrict__ bias, _Float16* __restrict__ Ch,
                 const _Float16* __restrict__ uh, const float* __restrict__ x_proj,
                 float* __restrict__ Clast) {
    const int tid = threadIdx.x;
    if (blockIdx.x == 16) {
        if (blockIdx.y >= 16) return;
        const int wave = tid >> 6, lane = tid & 63;
        const int task = blockIdx.y * 4 + wave;   // 64 tasks
        const int s_idx = task & 15, b = task >> 4;
        const _Float16* ur = uh + ((size_t)b * Ln + (Ln - 1)) * DIn;
        const float* w = x_proj + (size_t)(XPW + s_idx) * DIn;
        float s = 0.f;
        for (int k = lane; k < DIn; k += 64) s += (float)ur[k] * w[k];
        for (int off = 32; off > 0; off >>= 1) s += __shfl_down(s, off);
        if (lane == 0) Clast[b * DSn + s_idx] = s;
        return;
    }
    __shared__ _Float16 As[128 * 32];
    __shared__ _Float16 Bs[128 * 32];
    const int lane = tid & 63, wid = tid >> 6;
    const int wm = wid >> 1, wn = wid & 1;
    const int m0 = blockIdx.y * 128, n0 = blockIdx.x * 128;

    f32x4 acc[4][4] = {};
    for (int k0 = 0; k0 < DTRn; k0 += 32) {
        #pragma unroll
        for (int i = 0; i < 2; ++i) {
            const int off = tid * 16 + i * 4096;
            const int row = off >> 6;
            const int ch  = (off & 63) >> 1;
            __builtin_amdgcn_global_load_lds(
                (const __attribute__((address_space(1))) void*)(A + (size_t)(m0 + row) * XPW + k0 + ch),
                (__attribute__((address_space(3))) void*)(&As[off >> 1]), 16, 0, 0);
            __builtin_amdgcn_global_load_lds(
                (const __attribute__((address_space(1))) void*)(Bw + (size_t)(n0 + row) * DTRn + k0 + ch),
                (__attribute__((address_space(3))) void*)(&Bs[off >> 1]), 16, 0, 0);
        }
        __syncthreads();
        const int ar = lane & 15;
        const int kq = (lane >> 4) * 8;
        half8 af[4], bf[4];
        #pragma unroll
        for (int i = 0; i < 4; ++i)
            af[i] = *(const half8*)&As[(wm * 64 + i * 16 + ar) * 32 + kq];
        #pragma unroll
        for (int j = 0; j < 4; ++j)
            bf[j] = *(const half8*)&Bs[(wn * 64 + j * 16 + ar) * 32 + kq];
        #pragma unroll
        for (int i = 0; i < 4; ++i)
            #pragma unroll
            for (int j = 0; j < 4; ++j)
                acc[i][j] = __builtin_amdgcn_mfma_f32_16x16x32_f16(af[i], bf[j], acc[i][j], 0, 0, 0);
        __syncthreads();
    }
    const int cr = (lane >> 4) * 4;
    const int cn = lane & 15;
    #pragma unroll
    for (int i = 0; i < 4; ++i)
        #pragma unroll
        for (int j = 0; j < 4; ++j) {
            const int n = n0 + wn * 64 + j * 16 + cn;
            #pragma unroll
            for (int r = 0; r < 4; ++r) {
                const int m = m0 + wm * 64 + i * 16 + cr + r;
                Ch[(size_t)m * DIn + n] = (_Float16)softplus_(acc[i][j][r] + bias[n]);
            }
        }
}

// ---------------- chunked scan (powers-trick, proven) ----------------
__global__ __launch_bounds__(256)
void scan_chunk_kernel(const _Float16* __restrict__ delta, const _Float16* __restrict__ u,
                       const _Float16* __restrict__ dtBh, const float* __restrict__ A_log,
                       float* __restrict__ cS, _Float16* __restrict__ cH) {
    const int d = blockIdx.x * 256 + threadIdx.x;
    const int c = blockIdx.y, b = blockIdx.z;
    float A[DSn], h[DSn];
    const float4* al = (const float4*)(A_log + (size_t)d * DSn);
    #pragma unroll
    for (int q = 0; q < 4; ++q) {
        const float4 v = al[q];
        A[q * 4 + 0] = -__expf(v.x); A[q * 4 + 1] = -__expf(v.y);
        A[q * 4 + 2] = -__expf(v.z); A[q * 4 + 3] = -__expf(v.w);
        h[q * 4 + 0] = 0.f; h[q * 4 + 1] = 0.f; h[q * 4 + 2] = 0.f; h[q * 4 + 3] = 0.f;
    }
    const float A0 = A[0];
    bool structured = true;
    #pragma unroll
    for (int s = 1; s < DSn; ++s)
        structured = structured && (fabsf(A[s] - (float)(s + 1) * A0) <= 1e-4f * (s + 1));
    float Ssum = 0.f;
    const size_t base = ((size_t)b * Ln + (size_t)c * CHUNK) * DIn + d;
    const _Float16* Bp = dtBh + ((size_t)b * Ln + (size_t)c * CHUNK) * XPW + DTRn;
    if (structured) {
        #pragma unroll 4
        for (int tt = 0; tt < CHUNK; ++tt) {
            const float dl = (float)delta[base + (size_t)tt * DIn];
            const float uu = (float)u[base + (size_t)tt * DIn];
            const float du = dl * uu;
            Ssum += dl;
            const half8 bv0 = *(const half8*)(Bp + tt * XPW);
            const half8 bv1 = *(const half8*)(Bp + tt * XPW + 8);
            float Bv[DSn];
            #pragma unroll
            for (int q = 0; q < 8; ++q) { Bv[q] = (float)bv0[q]; Bv[8 + q] = (float)bv1[q]; }
            const float e1 = __expf(dl * A0);
            const float e2 = e1 * e1, e4 = e2 * e2, e8 = e4 * e4;
            float E[DSn];
            E[0] = e1;      E[1] = e2;      E[2] = e2 * e1;  E[3] = e4;
            E[4] = e4 * e1; E[5] = e4 * e2; E[6] = E[5] * e1; E[7] = e8;
            E[8] = e8 * e1; E[9] = e8 * e2; E[10] = E[9] * e1; E[11] = e8 * e4;
            E[12] = E[11] * e1; E[13] = E[11] * e2; E[14] = E[13] * e1; E[15] = e8 * e8;
            #pragma unroll
            for (int s = 0; s < DSn; ++s) h[s] = E[s] * h[s] + du * Bv[s];
        }
    } else {
        #pragma unroll 4
        for (int tt = 0; tt < CHUNK; ++tt) {
            const float dl = (float)delta[base + (size_t)tt * DIn];
            const float uu = (float)u[base + (size_t)tt * DIn];
            const float du = dl * uu;
            Ssum += dl;
            const half8 bv0 = *(const half8*)(Bp + tt * XPW);
            const half8 bv1 = *(const half8*)(Bp + tt * XPW + 8);
            float Bv[DSn];
            #pragma unroll
            for (int q = 0; q < 8; ++q) { Bv[q] = (float)bv0[q]; Bv[8 + q] = (float)bv1[q]; }
            #pragma unroll
            for (int s = 0; s < DSn; ++s) h[s] = __expf(dl * A[s]) * h[s] + du * Bv[s];
        }
    }
    const size_t cidx = ((size_t)b * NCHUNK + c) * DIn + d;
    cS[cidx] = Ssum;
    half8 o0, o1;
    #pragma unroll
    for (int q = 0; q < 8; ++q) { o0[q] = (_Float16)h[q]; o1[q] = (_Float16)h[8 + q]; }
    *(half8*)(cH + cidx * DSn) = o0;
    *(half8*)(cH + cidx * DSn + 8) = o1;
}

// ------- combine: fold chunks + gate + weff dot + atomic out (proven) -------
__global__ __launch_bounds__(256)
void combine_v3(const float* __restrict__ cS, const _Float16* __restrict__ cH,
                const float* __restrict__ A_log, const float* __restrict__ Clast,
                const float* __restrict__ Dp, const _Float16* __restrict__ u,
                const float* __restrict__ zlast, const float* __restrict__ wp,
                float* __restrict__ out) {
    __shared__ float acc[16];
    const int tid = threadIdx.x;
    const int s = tid & 15;
    const int d = blockIdx.x * 16 + (tid >> 4);
    const int b = blockIdx.y;
    const float A = -__expf(A_log[(size_t)d * DSn + s]);
    float h = 0.f;
    const size_t cb0 = (size_t)b * NCHUNK;
    for (int c = 0; c < NCHUNK; ++c) {
        const size_t cidx = (cb0 + c) * DIn + d;
        h = __expf(A * cS[cidx]) * h + (float)cH[cidx * DSn + s];
    }
    float y = h * Clast[b * DSn + s];
    y += __shfl_xor(y, 1);
    y += __shfl_xor(y, 2);
    y += __shfl_xor(y, 4);
    y += __shfl_xor(y, 8);
    if (s == 0) {
        const float ul = (float)u[((size_t)b * Ln + (Ln - 1)) * DIn + d];
        float yy = y + Dp[d] * ul;
        yy *= silu_(zlast[(size_t)b * DIn + d]);
        float w = 0.f;
        #pragma unroll
        for (int c = 0; c < WCH; ++c) w += wp[(size_t)c * DIn + d];
        acc[tid >> 4] = yy * w;
    }
    __syncthreads();
    if (tid == 0) {
        float t = 0.f;
        #pragma unroll
        for (int i = 0; i < 16; ++i) t += acc[i];
        atomicAdd(&out[b], t);
    }
}

} // namespace

extern "C" void kernel_launch(void* const* d_in, const int* in_sizes, int n_in,
                              void* d_out, int out_size, void* d_ws, size_t ws_size,
                              hipStream_t stream) {
    (void)in_sizes; (void)n_in; (void)out_size; (void)ws_size;
    const float* x       = (const float*)d_in[0];
    const float* W_emb   = (const float*)d_in[1];
    const float* b_emb   = (const float*)d_in[2];
    const float* in_proj = (const float*)d_in[3];
    const float* conv_w  = (const float*)d_in[4];
    const float* conv_b  = (const float*)d_in[5];
    const float* x_proj  = (const float*)d_in[6];
    const float* dt_w    = (const float*)d_in[7];
    const float* dt_b    = (const float*)d_in[8];
    const float* A_log   = (const float*)d_in[9];
    const float* Dp      = (const float*)d_in[10];
    const float* out_w   = (const float*)d_in[11];
    const float* fc_w    = (const float*)d_in[12];
    const float* fc_b    = (const float*)d_in[13];
    float* out = (float*)d_out;
    char* w8 = (char*)d_ws;

    const size_t MB = 1ull << 20;
    _Float16* upreh    = (_Float16*)(w8);            // 16 MB [upre -> conv]
    _Float16* uh       = (_Float16*)(w8 + 16 * MB);  // 16 MB [conv -> dtb/scan/combine]
    float*    wfoldP   = (float*)(w8 + 32 * MB);     // 16 MB [wfold partials]
    _Float16* deltah   = (_Float16*)(w8 + 32 * MB);  // aliases wfoldP [delta -> scan]
    float*    skp      = (float*)(w8 + 48 * MB);     // 10.5 MB [dtb partials]
    float*    cS       = skp;                        // aliases skp [scan -> combine]
    _Float16* cH       = (_Float16*)(w8 + 50 * MB);  // 16.8 MB [scan -> combine]
    _Float16* dtBh     = (_Float16*)(w8 + 67 * MB);
    _Float16* xh       = (_Float16*)(w8 + 68 * MB);
    _Float16* W_embT_h = (_Float16*)(w8 + 70 * MB);
    _Float16* in_projh = (_Float16*)(w8 + 71 * MB);  // 8 MB
    _Float16* xp_h     = (_Float16*)(w8 + 79 * MB);
    _Float16* dt_wh    = (_Float16*)(w8 + 80 * MB);
    _Float16* Wfoldh   = (_Float16*)(w8 + 81 * MB);  // 2 MB
    float*    wp       = (float*)(w8 + 83 * MB);
    float*    badd     = (float*)(w8 + 84 * MB);
    float*    zlast    = badd + 4096;
    float*    Clast    = zlast + (size_t)Bn * DIn;
    int*      cnt      = (int*)(w8 + 85 * MB);       // 96 ints (64 wfold + 32 dtb)

    // 1. prep: conversions + weff + badd + out init + counter zero
    prep_mega<<<6017, 256, 0, stream>>>(x, xh, in_proj, in_projh, dt_w, dt_wh,
                                        W_emb, W_embT_h, x_proj, xp_h,
                                        fc_w, out_w, wp, b_emb, badd, fc_b, out, cnt);
    // 2. Wfold = in_proj @ W_emb (split-K 4 + last-block reduce -> fp16)
    wfold_fused<<<dim3(4, ML / 128, 2), 256, 0, stream>>>(
        in_projh, W_embT_h, wfoldP, Wfoldh, cnt);
    // 3. upre = fp16(x @ Wfold_u^T + badd_u), K=256
    hgemm_upre<<<dim3(DIn / 128, ML / 128), 256, 0, stream>>>(xh, Wfoldh, badd, upreh);
    // 4. uh = silu(conv(upre)+cb); z_last fold GEMV
    conv_zlast<<<1056, 256, 0, stream>>>(upreh, conv_w, conv_b, uh, x, Wfoldh, badd, zlast);
    // 5. dtB = uh @ xp^T (split-K 8 + last-block reduce -> fp16)
    dtb_fused<<<dim3(8, ML / 128), 256, 0, stream>>>(uh, xp_h, skp, dtBh, cnt);
    // 6. delta = fp16(softplus(dtB @ dt_w^T + dt_b)) + clast
    delta_clast<<<dim3(17, ML / 128), 256, 0, stream>>>(
        dtBh, dt_wh, dt_b, deltah, uh, x_proj, Clast);
    // 7. chunked scan (cS aliases skp, dead now)
    scan_chunk_kernel<<<dim3(DIn / 256, NCHUNK, Bn), 256, 0, stream>>>(
        deltah, uh, dtBh, A_log, cS, cH);
    // 8. combine + gate + weff dot + atomic out
    combine_v3<<<dim3(DIn / 16, Bn), 256, 0, stream>>>(
        cS, cH, A_log, Clast, Dp, uh, zlast, wp, out);
}

// Round 12
// 130.236 us; speedup vs baseline: 3.2977x; 1.0980x over previous
//
#include <hip/hip_runtime.h>
#include <cstddef>
#include <cstdint>

namespace {

typedef _Float16 half8 __attribute__((ext_vector_type(8)));
typedef _Float16 half4 __attribute__((ext_vector_type(4)));
typedef float f32x4 __attribute__((ext_vector_type(4)));

constexpr int Bn   = 4;
constexpr int Ln   = 1024;
constexpr int INn  = 256;
constexpr int DMn  = 1024;
constexpr int DSn  = 16;
constexpr int DCn  = 4;
constexpr int DIn  = 2048;
constexpr int DTRn = 64;
constexpr int XPW  = DTRn + DSn;    // 80
constexpr int NCHUNK = 64;
constexpr int CHUNK  = Ln / NCHUNK; // 16
constexpr int WCH  = 32;
constexpr int ML   = Bn * Ln;       // 4096

__device__ __forceinline__ float silu_(float x) { return x / (1.f + __expf(-x)); }
__device__ __forceinline__ float softplus_(float x) {
    return fmaxf(x, 0.f) + __logf(1.f + __expf(-fabsf(x)));
}

// ================= prep (block-range dispatch), proven R7 version =================
__global__ __launch_bounds__(256)
void prep_mega(const float* __restrict__ x, _Float16* __restrict__ xh,
               const float* __restrict__ ip, _Float16* __restrict__ iph,
               const float* __restrict__ dtw, _Float16* __restrict__ dtwh,
               const float* __restrict__ W_emb, _Float16* __restrict__ W_embT,
               const float* __restrict__ x_proj, _Float16* __restrict__ xp_h,
               const float* __restrict__ fc_w, const float* __restrict__ out_w,
               float* __restrict__ wp,
               const float* __restrict__ b_emb, float* __restrict__ badd,
               const float* __restrict__ fc_b, float* __restrict__ out) {
    __shared__ float tile[32][33];
    const int bid = blockIdx.x, tid = threadIdx.x;
    if (bid < 4096) {
        const int n = bid;
        const float4 v = ((const float4*)ip)[n * 256 + tid];
        ((half4*)iph)[n * 256 + tid] =
            half4{(_Float16)v.x, (_Float16)v.y, (_Float16)v.z, (_Float16)v.w};
        const float4 bv = ((const float4*)b_emb)[tid];
        float s = v.x * bv.x + v.y * bv.y + v.z * bv.z + v.w * bv.w;
        for (int off = 32; off > 0; off >>= 1) s += __shfl_down(s, off);
        if ((tid & 63) == 0) tile[0][tid >> 6] = s;
        __syncthreads();
        if (tid == 0) badd[n] = tile[0][0] + tile[0][1] + tile[0][2] + tile[0][3];
    } else if (bid < 5248) {
        const float* in; _Float16* outp; int i;
        if (bid < 5120) { in = x;   outp = xh;   i = (bid - 4096) * 256 + tid; }
        else            { in = dtw; outp = dtwh; i = (bid - 5120) * 256 + tid; }
        const float4 v = ((const float4*)in)[i];
        ((half4*)outp)[i] = half4{(_Float16)v.x, (_Float16)v.y, (_Float16)v.z, (_Float16)v.w};
    } else if (bid < 5504) {
        const int bx = bid - 5248;
        const int m0 = (bx & 31) * 32, c0 = (bx >> 5) * 32;
        const int lc = tid & 31, lr = tid >> 5;
        #pragma unroll
        for (int ph = 0; ph < 4; ++ph)
            tile[lr + ph * 8][lc] = W_emb[(size_t)(m0 + lr + ph * 8) * INn + c0 + lc];
        __syncthreads();
        #pragma unroll
        for (int ph = 0; ph < 4; ++ph)
            W_embT[(size_t)(c0 + lr + ph * 8) * DMn + m0 + lc] = (_Float16)tile[lc][lr + ph * 8];
    } else if (bid < 5760) {
        const int i = (bid - 5504) * 256 + tid;
        const int r = i >> 9;
        const int c4 = i & 511;
        half4 h;
        if (r < XPW) {
            const float4 v = ((const float4*)(x_proj + (size_t)r * DIn))[c4];
            h = half4{(_Float16)v.x, (_Float16)v.y, (_Float16)v.z, (_Float16)v.w};
        } else {
            h = half4{(_Float16)0.f, (_Float16)0.f, (_Float16)0.f, (_Float16)0.f};
        }
        ((half4*)(xp_h + (size_t)r * DIn))[c4] = h;
    } else if (bid < 6016) {
        const int bx = bid - 5760;
        const int d = (bx & 7) * 256 + tid;
        const int c = bx >> 3;
        const int mstep = DMn / WCH;
        float s = 0.f;
        for (int m = c * mstep; m < (c + 1) * mstep; ++m)
            s += fc_w[m] * out_w[(size_t)m * DIn + d];
        wp[(size_t)c * DIn + d] = s;
    } else {
        if (tid < Bn) out[tid] = fc_b[0];
    }
}

// ---------------- generic split-K MFMA GEMM -> fp32 partials (proven) ----------------
__global__ __launch_bounds__(256)
void skgemm2(const _Float16* __restrict__ A, int lda,
             const _Float16* __restrict__ Bw, int ldb,
             float* __restrict__ P, int N, int Kc) {
    __shared__ _Float16 As[128 * 32];
    __shared__ _Float16 Bs[128 * 32];
    const int tid  = threadIdx.x;
    const int lane = tid & 63, wid = tid >> 6;
    const int wm = wid >> 1, wn = wid & 1;
    const int sk = blockIdx.x;
    const int m0 = blockIdx.y * 128;
    const int n0 = blockIdx.z * 128;
    const int M  = gridDim.y * 128;

    f32x4 acc[4][4] = {};
    const int kbeg = sk * Kc;
    for (int k0 = kbeg; k0 < kbeg + Kc; k0 += 32) {
        #pragma unroll
        for (int i = 0; i < 2; ++i) {
            const int off = tid * 16 + i * 4096;
            const int row = off >> 6;
            const int ch  = (off & 63) >> 1;
            __builtin_amdgcn_global_load_lds(
                (const __attribute__((address_space(1))) void*)(A + (size_t)(m0 + row) * lda + k0 + ch),
                (__attribute__((address_space(3))) void*)(&As[off >> 1]), 16, 0, 0);
            __builtin_amdgcn_global_load_lds(
                (const __attribute__((address_space(1))) void*)(Bw + (size_t)(n0 + row) * ldb + k0 + ch),
                (__attribute__((address_space(3))) void*)(&Bs[off >> 1]), 16, 0, 0);
        }
        __syncthreads();
        const int ar = lane & 15;
        const int kq = (lane >> 4) * 8;
        half8 af[4], bf[4];
        #pragma unroll
        for (int i = 0; i < 4; ++i)
            af[i] = *(const half8*)&As[(wm * 64 + i * 16 + ar) * 32 + kq];
        #pragma unroll
        for (int j = 0; j < 4; ++j)
            bf[j] = *(const half8*)&Bs[(wn * 64 + j * 16 + ar) * 32 + kq];
        #pragma unroll
        for (int i = 0; i < 4; ++i)
            #pragma unroll
            for (int j = 0; j < 4; ++j)
                acc[i][j] = __builtin_amdgcn_mfma_f32_16x16x32_f16(af[i], bf[j], acc[i][j], 0, 0, 0);
        __syncthreads();
    }
    const int cr = (lane >> 4) * 4;
    const int cn = lane & 15;
    #pragma unroll
    for (int i = 0; i < 4; ++i)
        #pragma unroll
        for (int j = 0; j < 4; ++j) {
            const int n = n0 + wn * 64 + j * 16 + cn;
            if (n < N) {
                #pragma unroll
                for (int r = 0; r < 4; ++r) {
                    const int m = m0 + wm * 64 + i * 16 + cr + r;
                    P[((size_t)sk * M + m) * N + n] = acc[i][j][r];
                }
            }
        }
}

// sum split-K partials -> fp16 (Wfold)
__global__ __launch_bounds__(256)
void skcomb(const float* __restrict__ P, _Float16* __restrict__ out, int total, int nsk) {
    const int i = blockIdx.x * 256 + threadIdx.x;
    if (i >= total) return;
    float s = 0.f;
    for (int k = 0; k < nsk; ++k) s += P[(size_t)k * total + i];
    out[i] = (_Float16)s;
}

// skcomb for dtB (blocks [0,1280)) + clast (blocks [1280,1296)) — proven R7
__global__ __launch_bounds__(256)
void skcombB_clast(const float* __restrict__ P, _Float16* __restrict__ dtBh,
                   const _Float16* __restrict__ u, const float* __restrict__ x_proj,
                   float* __restrict__ Clast) {
    const int bid = blockIdx.x, tid = threadIdx.x;
    if (bid < 1280) {
        const int i = bid * 256 + tid;
        float s = 0.f;
        #pragma unroll
        for (int k = 0; k < 8; ++k) s += P[(size_t)k * (ML * XPW) + i];
        dtBh[i] = (_Float16)s;
    } else {
        const int wave = tid >> 6, lane = tid & 63;
        const int task = (bid - 1280) * 4 + wave;
        const int s_idx = task & 15, b = task >> 4;
        const _Float16* ur = u + ((size_t)b * Ln + (Ln - 1)) * DIn;
        const float* w = x_proj + (size_t)(XPW + s_idx) * DIn;
        float s = 0.f;
        for (int k = lane; k < DIn; k += 64) s += (float)ur[k] * w[k];
        for (int off = 32; off > 0; off >>= 1) s += __shfl_down(s, off);
        if (lane == 0) Clast[b * DSn + s_idx] = s;
    }
}

// ---------------- MFMA fp16 GEMM (upre: fp16 + bias epilogue, proven) ----------
__global__ __launch_bounds__(256)
void hgemm_upre(const _Float16* __restrict__ A, const _Float16* __restrict__ Bw,
                const float* __restrict__ bias, _Float16* __restrict__ Ch) {
    __shared__ _Float16 As[128 * 32];
    __shared__ _Float16 Bs[128 * 32];
    const int tid  = threadIdx.x;
    const int lane = tid & 63, wid = tid >> 6;
    const int wm = wid >> 1, wn = wid & 1;
    const int m0 = blockIdx.y * 128, n0 = blockIdx.x * 128;

    f32x4 acc[4][4] = {};
    for (int k0 = 0; k0 < INn; k0 += 32) {
        #pragma unroll
        for (int i = 0; i < 2; ++i) {
            const int off = tid * 16 + i * 4096;
            const int row = off >> 6;
            const int ch  = (off & 63) >> 1;
            __builtin_amdgcn_global_load_lds(
                (const __attribute__((address_space(1))) void*)(A + (size_t)(m0 + row) * INn + k0 + ch),
                (__attribute__((address_space(3))) void*)(&As[off >> 1]), 16, 0, 0);
            __builtin_amdgcn_global_load_lds(
                (const __attribute__((address_space(1))) void*)(Bw + (size_t)(n0 + row) * INn + k0 + ch),
                (__attribute__((address_space(3))) void*)(&Bs[off >> 1]), 16, 0, 0);
        }
        __syncthreads();
        const int ar = lane & 15;
        const int kq = (lane >> 4) * 8;
        half8 af[4], bf[4];
        #pragma unroll
        for (int i = 0; i < 4; ++i)
            af[i] = *(const half8*)&As[(wm * 64 + i * 16 + ar) * 32 + kq];
        #pragma unroll
        for (int j = 0; j < 4; ++j)
            bf[j] = *(const half8*)&Bs[(wn * 64 + j * 16 + ar) * 32 + kq];
        #pragma unroll
        for (int i = 0; i < 4; ++i)
            #pragma unroll
            for (int j = 0; j < 4; ++j)
                acc[i][j] = __builtin_amdgcn_mfma_f32_16x16x32_f16(af[i], bf[j], acc[i][j], 0, 0, 0);
        __syncthreads();
    }
    const int cr = (lane >> 4) * 4;
    const int cn = lane & 15;
    #pragma unroll
    for (int i = 0; i < 4; ++i)
        #pragma unroll
        for (int j = 0; j < 4; ++j) {
            const int n = n0 + wn * 64 + j * 16 + cn;
            #pragma unroll
            for (int r = 0; r < 4; ++r) {
                const int m = m0 + wm * 64 + i * 16 + cr + r;
                Ch[(size_t)m * DIn + n] = (_Float16)(acc[i][j][r] + bias[n]);
            }
        }
}

// ------- conv+silu (blocks [0,1024)) + z_last fold GEMV (blocks [1024,1056)) -------
__global__ __launch_bounds__(256)
void conv_zlast(const _Float16* __restrict__ upre, const float* __restrict__ cw,
                const float* __restrict__ cb, _Float16* __restrict__ uh,
                const float* __restrict__ x, const _Float16* __restrict__ Wfh,
                const float* __restrict__ badd, float* __restrict__ zlast) {
    const int tid = threadIdx.x;
    const int bid = blockIdx.x;
    if (bid < 1024) {
        const int b  = bid >> 8;
        const int t0 = (bid & 255) * 4;
        const int d0 = tid * 8;
        const size_t rowbase = ((size_t)b * Ln + t0) * DIn + d0;
        half8 hzero;
        #pragma unroll
        for (int q = 0; q < 8; ++q) hzero[q] = (_Float16)0.f;
        half8 rows[7];
        if (t0 >= 3) {
            #pragma unroll
            for (int r = 0; r < 7; ++r)
                rows[r] = *(const half8*)(upre + rowbase + (ptrdiff_t)(r - 3) * DIn);
        } else {
            #pragma unroll
            for (int r = 0; r < 7; ++r) {
                const int t = t0 - 3 + r;
                rows[r] = (t >= 0) ? *(const half8*)(upre + rowbase + (ptrdiff_t)(r - 3) * DIn) : hzero;
            }
        }
        f32x4 cwq[8];
        float cbv[8];
        #pragma unroll
        for (int q = 0; q < 8; ++q) {
            cwq[q] = *(const f32x4*)(cw + (size_t)(d0 + q) * DCn);
            cbv[q] = cb[d0 + q];
        }
        #pragma unroll
        for (int s = 0; s < 4; ++s) {
            half8 o;
            #pragma unroll
            for (int q = 0; q < 8; ++q) {
                float acc = cbv[q];
                #pragma unroll
                for (int j = 0; j < DCn; ++j) acc += (float)rows[s + j][q] * cwq[q][j];
                o[q] = (_Float16)silu_(acc);
            }
            *(half8*)(uh + rowbase + (size_t)s * DIn) = o;
        }
    } else {
        const int t = (bid - 1024) * 256 + tid;
        const int j = t & (DIn - 1), b = t >> 11;
        const float4* x4 = (const float4*)(x + ((size_t)b * Ln + (Ln - 1)) * INn);
        const half4* w4 = (const half4*)(Wfh + (size_t)(DIn + j) * INn);
        float s = 0.f;
        #pragma unroll 8
        for (int q = 0; q < 64; ++q) {
            const float4 xv = x4[q];
            const half4 wv = w4[q];
            s += (float)wv[0] * xv.x + (float)wv[1] * xv.y
               + (float)wv[2] * xv.z + (float)wv[3] * xv.w;
        }
        zlast[(size_t)b * DIn + j] = s + badd[DIn + j];
    }
}

// ======== delta_scan: delta GEMM (K=64, softplus -> LDS) + in-block chunked scan ========
// grid (16 n-tiles, 32 m-tiles). Block tile = 128 t-rows x 128 d-cols
// = exactly 8 scan chunks x 128 d. delta never touches global memory.
__global__ __launch_bounds__(256)
void delta_scan(const _Float16* __restrict__ dtBh, const _Float16* __restrict__ dtwh,
                const float* __restrict__ dt_b, const _Float16* __restrict__ uh,
                const float* __restrict__ A_log,
                float* __restrict__ cS, _Float16* __restrict__ cH) {
    __shared__ _Float16 As[128 * 32];
    __shared__ _Float16 Bs[128 * 32];    // K-loop B-tiles; then Bv rows [128][16]
    __shared__ _Float16 Ds[128][132];    // softplus(delta) tile, padded
    const int tid = threadIdx.x;
    const int lane = tid & 63, wid = tid >> 6;
    const int wm = wid >> 1, wn = wid & 1;
    const int m0 = blockIdx.y * 128, n0 = blockIdx.x * 128;

    // ---- phase A: delta tile = dtBh[m0..,0..64) @ dtwh[n0..,0..64)^T ----
    f32x4 acc[4][4] = {};
    for (int k0 = 0; k0 < DTRn; k0 += 32) {
        #pragma unroll
        for (int i = 0; i < 2; ++i) {
            const int off = tid * 16 + i * 4096;
            const int row = off >> 6;
            const int ch  = (off & 63) >> 1;
            __builtin_amdgcn_global_load_lds(
                (const __attribute__((address_space(1))) void*)(dtBh + (size_t)(m0 + row) * XPW + k0 + ch),
                (__attribute__((address_space(3))) void*)(&As[off >> 1]), 16, 0, 0);
            __builtin_amdgcn_global_load_lds(
                (const __attribute__((address_space(1))) void*)(dtwh + (size_t)(n0 + row) * DTRn + k0 + ch),
                (__attribute__((address_space(3))) void*)(&Bs[off >> 1]), 16, 0, 0);
        }
        __syncthreads();
        const int ar = lane & 15;
        const int kq = (lane >> 4) * 8;
        half8 af[4], bf[4];
        #pragma unroll
        for (int i = 0; i < 4; ++i)
            af[i] = *(const half8*)&As[(wm * 64 + i * 16 + ar) * 32 + kq];
        #pragma unroll
        for (int j = 0; j < 4; ++j)
            bf[j] = *(const half8*)&Bs[(wn * 64 + j * 16 + ar) * 32 + kq];
        #pragma unroll
        for (int i = 0; i < 4; ++i)
            #pragma unroll
            for (int j = 0; j < 4; ++j)
                acc[i][j] = __builtin_amdgcn_mfma_f32_16x16x32_f16(af[i], bf[j], acc[i][j], 0, 0, 0);
        __syncthreads();
    }

    // ---- phase B: Bv rows (dtBh cols 64..79) -> Bs; softplus(delta) -> Ds ----
    {
        const int row = tid >> 1, off = (tid & 1) * 8;
        *(half8*)&Bs[row * 16 + off] =
            *(const half8*)(dtBh + (size_t)(m0 + row) * XPW + 64 + off);
    }
    {
        const int cr = (lane >> 4) * 4;
        const int cn = lane & 15;
        #pragma unroll
        for (int i = 0; i < 4; ++i)
            #pragma unroll
            for (int j = 0; j < 4; ++j) {
                const int ln = wn * 64 + j * 16 + cn;
                const float bb = dt_b[n0 + ln];
                #pragma unroll
                for (int r = 0; r < 4; ++r) {
                    const int lm = wm * 64 + i * 16 + cr + r;
                    Ds[lm][ln] = (_Float16)softplus_(acc[i][j][r] + bb);
                }
            }
    }
    __syncthreads();

    // ---- phase C: scan 8 chunks x 128 d (4 chunks per thread) ----
    const int bb = m0 >> 10;          // batch
    const int tb = m0 & 1023;         // t base within batch
    const int dcol = tid & 127;
    const int d = n0 + dcol;
    float A[DSn];
    {
        const float4* al = (const float4*)(A_log + (size_t)d * DSn);
        #pragma unroll
        for (int q = 0; q < 4; ++q) {
            const float4 v = al[q];
            A[q * 4 + 0] = -__expf(v.x); A[q * 4 + 1] = -__expf(v.y);
            A[q * 4 + 2] = -__expf(v.z); A[q * 4 + 3] = -__expf(v.w);
        }
    }
    const float A0 = A[0];
    bool structured = true;
    #pragma unroll
    for (int s = 1; s < DSn; ++s)
        structured = structured && (fabsf(A[s] - (float)(s + 1) * A0) <= 1e-4f * (s + 1));

    for (int ci = (tid >> 7); ci < 8; ci += 2) {
        float h[DSn];
        #pragma unroll
        for (int s = 0; s < DSn; ++s) h[s] = 0.f;
        float Ssum = 0.f;
        const size_t ubase = ((size_t)bb * Ln + tb + ci * 16) * DIn + d;
        if (structured) {
            for (int tt = 0; tt < CHUNK; ++tt) {
                const int lr = ci * 16 + tt;
                const float dl = (float)Ds[lr][dcol];
                const float uu = (float)uh[ubase + (size_t)tt * DIn];
                const float du = dl * uu;
                Ssum += dl;
                const half8 bv0 = *(const half8*)&Bs[lr * 16];
                const half8 bv1 = *(const half8*)&Bs[lr * 16 + 8];
                float Bv[DSn];
                #pragma unroll
                for (int q = 0; q < 8; ++q) { Bv[q] = (float)bv0[q]; Bv[8 + q] = (float)bv1[q]; }
                const float e1 = __expf(dl * A0);
                const float e2 = e1 * e1, e4 = e2 * e2, e8 = e4 * e4;
                float E[DSn];
                E[0] = e1;      E[1] = e2;      E[2] = e2 * e1;  E[3] = e4;
                E[4] = e4 * e1; E[5] = e4 * e2; E[6] = E[5] * e1; E[7] = e8;
                E[8] = e8 * e1; E[9] = e8 * e2; E[10] = E[9] * e1; E[11] = e8 * e4;
                E[12] = E[11] * e1; E[13] = E[11] * e2; E[14] = E[13] * e1; E[15] = e8 * e8;
                #pragma unroll
                for (int s = 0; s < DSn; ++s) h[s] = E[s] * h[s] + du * Bv[s];
            }
        } else {
            for (int tt = 0; tt < CHUNK; ++tt) {
                const int lr = ci * 16 + tt;
                const float dl = (float)Ds[lr][dcol];
                const float uu = (float)uh[ubase + (size_t)tt * DIn];
                const float du = dl * uu;
                Ssum += dl;
                const half8 bv0 = *(const half8*)&Bs[lr * 16];
                const half8 bv1 = *(const half8*)&Bs[lr * 16 + 8];
                float Bv[DSn];
                #pragma unroll
                for (int q = 0; q < 8; ++q) { Bv[q] = (float)bv0[q]; Bv[8 + q] = (float)bv1[q]; }
                #pragma unroll
                for (int s = 0; s < DSn; ++s) h[s] = __expf(dl * A[s]) * h[s] + du * Bv[s];
            }
        }
        const int c = (tb >> 4) + ci;
        const size_t cidx = ((size_t)bb * NCHUNK + c) * DIn + d;
        cS[cidx] = Ssum;
        half8 o0, o1;
        #pragma unroll
        for (int q = 0; q < 8; ++q) { o0[q] = (_Float16)h[q]; o1[q] = (_Float16)h[8 + q]; }
        *(half8*)(cH + cidx * DSn) = o0;
        *(half8*)(cH + cidx * DSn + 8) = o1;
    }
}

// ------- combine: fold chunks + gate + weff dot + atomic out (proven) -------
__global__ __launch_bounds__(256)
void combine_v3(const float* __restrict__ cS, const _Float16* __restrict__ cH,
                const float* __restrict__ A_log, const float* __restrict__ Clast,
                const float* __restrict__ Dp, const _Float16* __restrict__ u,
                const float* __restrict__ zlast, const float* __restrict__ wp,
                float* __restrict__ out) {
    __shared__ float acc[16];
    const int tid = threadIdx.x;
    const int s = tid & 15;
    const int d = blockIdx.x * 16 + (tid >> 4);
    const int b = blockIdx.y;
    const float A = -__expf(A_log[(size_t)d * DSn + s]);
    float h = 0.f;
    const size_t cb0 = (size_t)b * NCHUNK;
    for (int c = 0; c < NCHUNK; ++c) {
        const size_t cidx = (cb0 + c) * DIn + d;
        h = __expf(A * cS[cidx]) * h + (float)cH[cidx * DSn + s];
    }
    float y = h * Clast[b * DSn + s];
    y += __shfl_xor(y, 1);
    y += __shfl_xor(y, 2);
    y += __shfl_xor(y, 4);
    y += __shfl_xor(y, 8);
    if (s == 0) {
        const float ul = (float)u[((size_t)b * Ln + (Ln - 1)) * DIn + d];
        float yy = y + Dp[d] * ul;
        yy *= silu_(zlast[(size_t)b * DIn + d]);
        float w = 0.f;
        #pragma unroll
        for (int c = 0; c < WCH; ++c) w += wp[(size_t)c * DIn + d];
        acc[tid >> 4] = yy * w;
    }
    __syncthreads();
    if (tid == 0) {
        float t = 0.f;
        #pragma unroll
        for (int i = 0; i < 16; ++i) t += acc[i];
        atomicAdd(&out[b], t);
    }
}

} // namespace

extern "C" void kernel_launch(void* const* d_in, const int* in_sizes, int n_in,
                              void* d_out, int out_size, void* d_ws, size_t ws_size,
                              hipStream_t stream) {
    (void)in_sizes; (void)n_in; (void)out_size; (void)ws_size;
    const float* x       = (const float*)d_in[0];
    const float* W_emb   = (const float*)d_in[1];
    const float* b_emb   = (const float*)d_in[2];
    const float* in_proj = (const float*)d_in[3];
    const float* conv_w  = (const float*)d_in[4];
    const float* conv_b  = (const float*)d_in[5];
    const float* x_proj  = (const float*)d_in[6];
    const float* dt_w    = (const float*)d_in[7];
    const float* dt_b    = (const float*)d_in[8];
    const float* A_log   = (const float*)d_in[9];
    const float* Dp      = (const float*)d_in[10];
    const float* out_w   = (const float*)d_in[11];
    const float* fc_w    = (const float*)d_in[12];
    const float* fc_b    = (const float*)d_in[13];
    float* out = (float*)d_out;
    char* w8 = (char*)d_ws;

    const size_t MB = 1ull << 20;
    _Float16* upreh    = (_Float16*)(w8);            // 16 MB [upre -> conv]
    _Float16* uh       = (_Float16*)(w8 + 16 * MB);  // 16 MB [conv -> dtb/delta_scan/combine]
    float*    wfoldP   = (float*)(w8 + 32 * MB);     // 16 MB [wfold -> skcomb]
    float*    skp      = (float*)(w8 + 48 * MB);     // 10.5 MB [dtb -> skcombB]
    float*    cS       = skp;                        // aliases skp [delta_scan -> combine]
    _Float16* cH       = (_Float16*)(w8 + 50 * MB);  // 16.8 MB [delta_scan -> combine]
    _Float16* dtBh     = (_Float16*)(w8 + 67 * MB);
    _Float16* xh       = (_Float16*)(w8 + 68 * MB);
    _Float16* W_embT_h = (_Float16*)(w8 + 70 * MB);
    _Float16* in_projh = (_Float16*)(w8 + 71 * MB);  // 8 MB
    _Float16* xp_h     = (_Float16*)(w8 + 79 * MB);
    _Float16* dt_wh    = (_Float16*)(w8 + 80 * MB);
    _Float16* Wfoldh   = (_Float16*)(w8 + 81 * MB);  // 2 MB
    float*    wp       = (float*)(w8 + 83 * MB);
    float*    badd     = (float*)(w8 + 84 * MB);
    float*    zlast    = badd + 4096;
    float*    Clast    = zlast + (size_t)Bn * DIn;

    // 1. prep: conversions + weff + badd + out init
    prep_mega<<<6017, 256, 0, stream>>>(x, xh, in_proj, in_projh, dt_w, dt_wh,
                                        W_emb, W_embT_h, x_proj, xp_h,
                                        fc_w, out_w, wp, b_emb, badd, fc_b, out);
    // 2. Wfold = in_proj @ W_emb (split-K 4)
    skgemm2<<<dim3(4, ML / 128, 2), 256, 0, stream>>>(
        in_projh, DMn, W_embT_h, DMn, wfoldP, INn, 256);
    // 3. Wfold partial sum -> fp16
    skcomb<<<(ML * INn + 255) / 256, 256, 0, stream>>>(wfoldP, Wfoldh, ML * INn, 4);
    // 4. upre = fp16(x @ Wfold_u^T + badd_u), K=256
    hgemm_upre<<<dim3(DIn / 128, ML / 128), 256, 0, stream>>>(xh, Wfoldh, badd, upreh);
    // 5. uh = silu(conv(upre)+cb); z_last fold GEMV
    conv_zlast<<<1056, 256, 0, stream>>>(upreh, conv_w, conv_b, uh, x, Wfoldh, badd, zlast);
    // 6. dtB partials = uh @ xp^T (split-K 8)
    skgemm2<<<dim3(8, ML / 128, 1), 256, 0, stream>>>(uh, DIn, xp_h, DIn, skp, XPW, 256);
    // 7. dtB partial sum -> fp16 + C_last
    skcombB_clast<<<1296, 256, 0, stream>>>(skp, dtBh, uh, x_proj, Clast);
    // 8. fused delta GEMM + chunked scan (delta never hits HBM; cS aliases skp, dead now)
    delta_scan<<<dim3(DIn / 128, ML / 128), 256, 0, stream>>>(
        dtBh, dt_wh, dt_b, uh, A_log, cS, cH);
    // 9. combine + gate + weff dot + atomic out
    combine_v3<<<dim3(DIn / 16, Bn), 256, 0, stream>>>(
        cS, cH, A_log, Clast, Dp, uh, zlast, wp, out);
}

// Round 13
// 124.633 us; speedup vs baseline: 3.4460x; 1.0450x over previous
//
#include <hip/hip_runtime.h>
#include <cstddef>
#include <cstdint>

namespace {

typedef _Float16 half8 __attribute__((ext_vector_type(8)));
typedef _Float16 half4 __attribute__((ext_vector_type(4)));
typedef float f32x4 __attribute__((ext_vector_type(4)));

constexpr int Bn   = 4;
constexpr int Ln   = 1024;
constexpr int INn  = 256;
constexpr int DMn  = 1024;
constexpr int DSn  = 16;
constexpr int DCn  = 4;
constexpr int DIn  = 2048;
constexpr int DTRn = 64;
constexpr int XPW  = DTRn + DSn;    // 80
constexpr int NCHUNK = 64;
constexpr int CHUNK  = Ln / NCHUNK; // 16
constexpr int WCH  = 32;
constexpr int ML   = Bn * Ln;       // 4096

__device__ __forceinline__ float silu_(float x) { return x / (1.f + __expf(-x)); }
__device__ __forceinline__ float softplus_(float x) {
    return fmaxf(x, 0.f) + __logf(1.f + __expf(-fabsf(x)));
}

// ================= prep (block-range dispatch), proven R7 version =================
__global__ __launch_bounds__(256)
void prep_mega(const float* __restrict__ x, _Float16* __restrict__ xh,
               const float* __restrict__ ip, _Float16* __restrict__ iph,
               const float* __restrict__ dtw, _Float16* __restrict__ dtwh,
               const float* __restrict__ W_emb, _Float16* __restrict__ W_embT,
               const float* __restrict__ x_proj, _Float16* __restrict__ xp_h,
               const float* __restrict__ fc_w, const float* __restrict__ out_w,
               float* __restrict__ wp,
               const float* __restrict__ b_emb, float* __restrict__ badd,
               const float* __restrict__ fc_b, float* __restrict__ out) {
    __shared__ float tile[32][33];
    const int bid = blockIdx.x, tid = threadIdx.x;
    if (bid < 4096) {
        const int n = bid;
        const float4 v = ((const float4*)ip)[n * 256 + tid];
        ((half4*)iph)[n * 256 + tid] =
            half4{(_Float16)v.x, (_Float16)v.y, (_Float16)v.z, (_Float16)v.w};
        const float4 bv = ((const float4*)b_emb)[tid];
        float s = v.x * bv.x + v.y * bv.y + v.z * bv.z + v.w * bv.w;
        for (int off = 32; off > 0; off >>= 1) s += __shfl_down(s, off);
        if ((tid & 63) == 0) tile[0][tid >> 6] = s;
        __syncthreads();
        if (tid == 0) badd[n] = tile[0][0] + tile[0][1] + tile[0][2] + tile[0][3];
    } else if (bid < 5248) {
        const float* in; _Float16* outp; int i;
        if (bid < 5120) { in = x;   outp = xh;   i = (bid - 4096) * 256 + tid; }
        else            { in = dtw; outp = dtwh; i = (bid - 5120) * 256 + tid; }
        const float4 v = ((const float4*)in)[i];
        ((half4*)outp)[i] = half4{(_Float16)v.x, (_Float16)v.y, (_Float16)v.z, (_Float16)v.w};
    } else if (bid < 5504) {
        const int bx = bid - 5248;
        const int m0 = (bx & 31) * 32, c0 = (bx >> 5) * 32;
        const int lc = tid & 31, lr = tid >> 5;
        #pragma unroll
        for (int ph = 0; ph < 4; ++ph)
            tile[lr + ph * 8][lc] = W_emb[(size_t)(m0 + lr + ph * 8) * INn + c0 + lc];
        __syncthreads();
        #pragma unroll
        for (int ph = 0; ph < 4; ++ph)
            W_embT[(size_t)(c0 + lr + ph * 8) * DMn + m0 + lc] = (_Float16)tile[lc][lr + ph * 8];
    } else if (bid < 5760) {
        const int i = (bid - 5504) * 256 + tid;
        const int r = i >> 9;
        const int c4 = i & 511;
        half4 h;
        if (r < XPW) {
            const float4 v = ((const float4*)(x_proj + (size_t)r * DIn))[c4];
            h = half4{(_Float16)v.x, (_Float16)v.y, (_Float16)v.z, (_Float16)v.w};
        } else {
            h = half4{(_Float16)0.f, (_Float16)0.f, (_Float16)0.f, (_Float16)0.f};
        }
        ((half4*)(xp_h + (size_t)r * DIn))[c4] = h;
    } else if (bid < 6016) {
        const int bx = bid - 5760;
        const int d = (bx & 7) * 256 + tid;
        const int c = bx >> 3;
        const int mstep = DMn / WCH;
        float s = 0.f;
        for (int m = c * mstep; m < (c + 1) * mstep; ++m)
            s += fc_w[m] * out_w[(size_t)m * DIn + d];
        wp[(size_t)c * DIn + d] = s;
    } else {
        if (tid < Bn) out[tid] = fc_b[0];
    }
}

// ---------------- generic split-K MFMA GEMM -> fp32 partials (proven) ----------------
__global__ __launch_bounds__(256)
void skgemm2(const _Float16* __restrict__ A, int lda,
             const _Float16* __restrict__ Bw, int ldb,
             float* __restrict__ P, int N, int Kc) {
    __shared__ _Float16 As[128 * 32];
    __shared__ _Float16 Bs[128 * 32];
    const int tid  = threadIdx.x;
    const int lane = tid & 63, wid = tid >> 6;
    const int wm = wid >> 1, wn = wid & 1;
    const int sk = blockIdx.x;
    const int m0 = blockIdx.y * 128;
    const int n0 = blockIdx.z * 128;
    const int M  = gridDim.y * 128;

    f32x4 acc[4][4] = {};
    const int kbeg = sk * Kc;
    for (int k0 = kbeg; k0 < kbeg + Kc; k0 += 32) {
        #pragma unroll
        for (int i = 0; i < 2; ++i) {
            const int off = tid * 16 + i * 4096;
            const int row = off >> 6;
            const int ch  = (off & 63) >> 1;
            __builtin_amdgcn_global_load_lds(
                (const __attribute__((address_space(1))) void*)(A + (size_t)(m0 + row) * lda + k0 + ch),
                (__attribute__((address_space(3))) void*)(&As[off >> 1]), 16, 0, 0);
            __builtin_amdgcn_global_load_lds(
                (const __attribute__((address_space(1))) void*)(Bw + (size_t)(n0 + row) * ldb + k0 + ch),
                (__attribute__((address_space(3))) void*)(&Bs[off >> 1]), 16, 0, 0);
        }
        __syncthreads();
        const int ar = lane & 15;
        const int kq = (lane >> 4) * 8;
        half8 af[4], bf[4];
        #pragma unroll
        for (int i = 0; i < 4; ++i)
            af[i] = *(const half8*)&As[(wm * 64 + i * 16 + ar) * 32 + kq];
        #pragma unroll
        for (int j = 0; j < 4; ++j)
            bf[j] = *(const half8*)&Bs[(wn * 64 + j * 16 + ar) * 32 + kq];
        #pragma unroll
        for (int i = 0; i < 4; ++i)
            #pragma unroll
            for (int j = 0; j < 4; ++j)
                acc[i][j] = __builtin_amdgcn_mfma_f32_16x16x32_f16(af[i], bf[j], acc[i][j], 0, 0, 0);
        __syncthreads();
    }
    const int cr = (lane >> 4) * 4;
    const int cn = lane & 15;
    #pragma unroll
    for (int i = 0; i < 4; ++i)
        #pragma unroll
        for (int j = 0; j < 4; ++j) {
            const int n = n0 + wn * 64 + j * 16 + cn;
            if (n < N) {
                #pragma unroll
                for (int r = 0; r < 4; ++r) {
                    const int m = m0 + wm * 64 + i * 16 + cr + r;
                    P[((size_t)sk * M + m) * N + n] = acc[i][j][r];
                }
            }
        }
}

// sum split-K partials -> fp16 (Wfold)
__global__ __launch_bounds__(256)
void skcomb(const float* __restrict__ P, _Float16* __restrict__ out, int total, int nsk) {
    const int i = blockIdx.x * 256 + threadIdx.x;
    if (i >= total) return;
    float s = 0.f;
    for (int k = 0; k < nsk; ++k) s += P[(size_t)k * total + i];
    out[i] = (_Float16)s;
}

// skcomb for dtB (blocks [0,1280)) + clast (blocks [1280,1296)) — proven R7
__global__ __launch_bounds__(256)
void skcombB_clast(const float* __restrict__ P, _Float16* __restrict__ dtBh,
                   const _Float16* __restrict__ u, const float* __restrict__ x_proj,
                   float* __restrict__ Clast) {
    const int bid = blockIdx.x, tid = threadIdx.x;
    if (bid < 1280) {
        const int i = bid * 256 + tid;
        float s = 0.f;
        #pragma unroll
        for (int k = 0; k < 8; ++k) s += P[(size_t)k * (ML * XPW) + i];
        dtBh[i] = (_Float16)s;
    } else {
        const int wave = tid >> 6, lane = tid & 63;
        const int task = (bid - 1280) * 4 + wave;
        const int s_idx = task & 15, b = task >> 4;
        const _Float16* ur = u + ((size_t)b * Ln + (Ln - 1)) * DIn;
        const float* w = x_proj + (size_t)(XPW + s_idx) * DIn;
        float s = 0.f;
        for (int k = lane; k < DIn; k += 64) s += (float)ur[k] * w[k];
        for (int off = 32; off > 0; off >>= 1) s += __shfl_down(s, off);
        if (lane == 0) Clast[b * DSn + s_idx] = s;
    }
}

// ======== upre_conv_zlast: upre GEMM (K=256, +16-row halo) -> LDS -> conv+silu -> uh ========
// grid (17, 32). x<16: GEMM+conv tile (128 t-rows x 128 d-cols, upre never hits HBM).
// x==16: zlast fold GEMV (32 blocks x 256 = 8192 tasks).
__global__ __launch_bounds__(256)
void upre_conv_zlast(const _Float16* __restrict__ xh, const _Float16* __restrict__ Wfoldh,
                     const float* __restrict__ badd,
                     const float* __restrict__ cw, const float* __restrict__ cb,
                     _Float16* __restrict__ uh,
                     const float* __restrict__ x, float* __restrict__ zlast) {
    const int tid = threadIdx.x;
    if (blockIdx.x == 16) {
        const int t = blockIdx.y * 256 + tid;
        const int j = t & (DIn - 1), b = t >> 11;
        const float4* x4 = (const float4*)(x + ((size_t)b * Ln + (Ln - 1)) * INn);
        const half4* w4 = (const half4*)(Wfoldh + (size_t)(DIn + j) * INn);
        float s = 0.f;
        #pragma unroll 8
        for (int q = 0; q < 64; ++q) {
            const float4 xv = x4[q];
            const half4 wv = w4[q];
            s += (float)wv[0] * xv.x + (float)wv[1] * xv.y
               + (float)wv[2] * xv.z + (float)wv[3] * xv.w;
        }
        zlast[(size_t)b * DIn + j] = s + badd[DIn + j];
        return;
    }
    // union: [GEMM phase] As 144x32 (4608) | Bs 128x32 (4096)  /  [conv phase] Ds[144][132]
    __shared__ _Float16 smem[144 * 132];
    _Float16* As = smem;            // 144 rows (x rows m0-16 .. m0+127)
    _Float16* Bs = smem + 144 * 32;
    _Float16 (*Ds)[132] = (_Float16 (*)[132])smem;

    const int lane = tid & 63, wid = tid >> 6;
    const int wm = wid >> 1, wn = wid & 1;
    const int m0 = blockIdx.y * 128, n0 = blockIdx.x * 128;

    f32x4 acc[4][4] = {};
    f32x4 acch[4] = {};             // halo rows (As rows 0..15), used by wm==0 waves
    for (int k0 = 0; k0 < INn; k0 += 32) {
        // stage As: 144 rows x 64 B
        #pragma unroll
        for (int i = 0; i < 2; ++i) {
            const int off = tid * 16 + i * 4096;
            const int row = off >> 6;
            const int ch  = (off & 63) >> 1;
            int srow = m0 - 16 + row;
            if (srow < 0) srow = 0;   // mt==0 halo: garbage, unused (t0==0 zeros in conv)
            __builtin_amdgcn_global_load_lds(
                (const __attribute__((address_space(1))) void*)(xh + (size_t)srow * INn + k0 + ch),
                (__attribute__((address_space(3))) void*)(&As[off >> 1]), 16, 0, 0);
            // stage Bs: 128 rows x 64 B
            const _Float16* gb = Wfoldh + (size_t)(n0 + row) * INn + k0 + ch;
            __builtin_amdgcn_global_load_lds(
                (const __attribute__((address_space(1))) void*)gb,
                (__attribute__((address_space(3))) void*)(&Bs[off >> 1]), 16, 0, 0);
        }
        if (tid < 64) {
            const int off = tid * 16 + 8192;   // As rows 128..143 (= x rows m0+112..m0+127)
            const int row = off >> 6;
            const int ch  = (off & 63) >> 1;
            __builtin_amdgcn_global_load_lds(
                (const __attribute__((address_space(1))) void*)(xh + (size_t)(m0 - 16 + row) * INn + k0 + ch),
                (__attribute__((address_space(3))) void*)(&As[off >> 1]), 16, 0, 0);
        }
        __syncthreads();
        const int ar = lane & 15;
        const int kq = (lane >> 4) * 8;
        half8 af[4], bf[4];
        #pragma unroll
        for (int i = 0; i < 4; ++i)
            af[i] = *(const half8*)&As[(16 + wm * 64 + i * 16 + ar) * 32 + kq];
        #pragma unroll
        for (int j = 0; j < 4; ++j)
            bf[j] = *(const half8*)&Bs[(wn * 64 + j * 16 + ar) * 32 + kq];
        #pragma unroll
        for (int i = 0; i < 4; ++i)
            #pragma unroll
            for (int j = 0; j < 4; ++j)
                acc[i][j] = __builtin_amdgcn_mfma_f32_16x16x32_f16(af[i], bf[j], acc[i][j], 0, 0, 0);
        if (wm == 0) {
            const half8 afh = *(const half8*)&As[ar * 32 + kq];
            #pragma unroll
            for (int j = 0; j < 4; ++j)
                acch[j] = __builtin_amdgcn_mfma_f32_16x16x32_f16(afh, bf[j], acch[j], 0, 0, 0);
        }
        __syncthreads();
    }

    // epilogue: fp16(acc + bias) -> Ds (overlays As/Bs; all LDS reads done)
    {
        const int cr = (lane >> 4) * 4;
        const int cn = lane & 15;
        #pragma unroll
        for (int i = 0; i < 4; ++i)
            #pragma unroll
            for (int j = 0; j < 4; ++j) {
                const int col = wn * 64 + j * 16 + cn;
                const float bb = badd[n0 + col];
                #pragma unroll
                for (int r = 0; r < 4; ++r)
                    Ds[16 + wm * 64 + i * 16 + cr + r][col] = (_Float16)(acc[i][j][r] + bb);
            }
        if (wm == 0) {
            #pragma unroll
            for (int j = 0; j < 4; ++j) {
                const int col = wn * 64 + j * 16 + cn;
                const float bb = badd[n0 + col];
                #pragma unroll
                for (int r = 0; r < 4; ++r)
                    Ds[cr + r][col] = (_Float16)(acch[j][r] + bb);
            }
        }
    }
    __syncthreads();

    // conv + silu: each thread fixes an 8-col group, walks 8 rows
    const int col8 = tid & 15;
    const int d0l = col8 * 8;
    f32x4 cwq[8];
    float cbv[8];
    #pragma unroll
    for (int q = 0; q < 8; ++q) {
        cwq[q] = *(const f32x4*)(cw + (size_t)(n0 + d0l + q) * DCn);
        cbv[q] = cb[n0 + d0l + q];
    }
    const int b  = m0 >> 10;
    const int t0 = m0 & 1023;
    half8 hzero;
    #pragma unroll
    for (int q = 0; q < 8; ++q) hzero[q] = (_Float16)0.f;
    for (int k = 0; k < 8; ++k) {
        const int rr = (tid >> 4) + k * 16;   // 0..127
        half8 w[4];
        #pragma unroll
        for (int jj = 0; jj < 4; ++jj) {
            const int dr = 16 + rr - 3 + jj;
            w[jj] = ((t0 == 0) && (dr < 16)) ? hzero : *(const half8*)&Ds[dr][d0l];
        }
        half8 o;
        #pragma unroll
        for (int q = 0; q < 8; ++q) {
            float a = cbv[q];
            #pragma unroll
            for (int jj = 0; jj < 4; ++jj) a += (float)w[jj][q] * cwq[q][jj];
            o[q] = (_Float16)silu_(a);
        }
        *(half8*)(uh + ((size_t)b * Ln + t0 + rr) * DIn + n0 + d0l) = o;
    }
}

// ---------------- MFMA fp16 GEMM (delta: softplus + bias, proven R7) ----------
__global__ __launch_bounds__(256)
void hgemm_delta(const _Float16* __restrict__ A, const _Float16* __restrict__ Bw,
                 const float* __restrict__ bias, _Float16* __restrict__ Ch) {
    __shared__ _Float16 As[128 * 32];
    __shared__ _Float16 Bs[128 * 32];
    const int tid  = threadIdx.x;
    const int lane = tid & 63, wid = tid >> 6;
    const int wm = wid >> 1, wn = wid & 1;
    const int m0 = blockIdx.y * 128, n0 = blockIdx.x * 128;

    f32x4 acc[4][4] = {};
    for (int k0 = 0; k0 < DTRn; k0 += 32) {
        #pragma unroll
        for (int i = 0; i < 2; ++i) {
            const int off = tid * 16 + i * 4096;
            const int row = off >> 6;
            const int ch  = (off & 63) >> 1;
            __builtin_amdgcn_global_load_lds(
                (const __attribute__((address_space(1))) void*)(A + (size_t)(m0 + row) * XPW + k0 + ch),
                (__attribute__((address_space(3))) void*)(&As[off >> 1]), 16, 0, 0);
            __builtin_amdgcn_global_load_lds(
                (const __attribute__((address_space(1))) void*)(Bw + (size_t)(n0 + row) * DTRn + k0 + ch),
                (__attribute__((address_space(3))) void*)(&Bs[off >> 1]), 16, 0, 0);
        }
        __syncthreads();
        const int ar = lane & 15;
        const int kq = (lane >> 4) * 8;
        half8 af[4], bf[4];
        #pragma unroll
        for (int i = 0; i < 4; ++i)
            af[i] = *(const half8*)&As[(wm * 64 + i * 16 + ar) * 32 + kq];
        #pragma unroll
        for (int j = 0; j < 4; ++j)
            bf[j] = *(const half8*)&Bs[(wn * 64 + j * 16 + ar) * 32 + kq];
        #pragma unroll
        for (int i = 0; i < 4; ++i)
            #pragma unroll
            for (int j = 0; j < 4; ++j)
                acc[i][j] = __builtin_amdgcn_mfma_f32_16x16x32_f16(af[i], bf[j], acc[i][j], 0, 0, 0);
        __syncthreads();
    }
    const int cr = (lane >> 4) * 4;
    const int cn = lane & 15;
    #pragma unroll
    for (int i = 0; i < 4; ++i)
        #pragma unroll
        for (int j = 0; j < 4; ++j) {
            const int n = n0 + wn * 64 + j * 16 + cn;
            #pragma unroll
            for (int r = 0; r < 4; ++r) {
                const int m = m0 + wm * 64 + i * 16 + cr + r;
                Ch[(size_t)m * DIn + n] = (_Float16)softplus_(acc[i][j][r] + bias[n]);
            }
        }
}

// ---------------- chunked scan (powers-trick, proven) ----------------
__global__ __launch_bounds__(256)
void scan_chunk_kernel(const _Float16* __restrict__ delta, const _Float16* __restrict__ u,
                       const _Float16* __restrict__ dtBh, const float* __restrict__ A_log,
                       float* __restrict__ cS, _Float16* __restrict__ cH) {
    const int d = blockIdx.x * 256 + threadIdx.x;
    const int c = blockIdx.y, b = blockIdx.z;
    float A[DSn], h[DSn];
    const float4* al = (const float4*)(A_log + (size_t)d * DSn);
    #pragma unroll
    for (int q = 0; q < 4; ++q) {
        const float4 v = al[q];
        A[q * 4 + 0] = -__expf(v.x); A[q * 4 + 1] = -__expf(v.y);
        A[q * 4 + 2] = -__expf(v.z); A[q * 4 + 3] = -__expf(v.w);
        h[q * 4 + 0] = 0.f; h[q * 4 + 1] = 0.f; h[q * 4 + 2] = 0.f; h[q * 4 + 3] = 0.f;
    }
    const float A0 = A[0];
    bool structured = true;
    #pragma unroll
    for (int s = 1; s < DSn; ++s)
        structured = structured && (fabsf(A[s] - (float)(s + 1) * A0) <= 1e-4f * (s + 1));
    float Ssum = 0.f;
    const size_t base = ((size_t)b * Ln + (size_t)c * CHUNK) * DIn + d;
    const _Float16* Bp = dtBh + ((size_t)b * Ln + (size_t)c * CHUNK) * XPW + DTRn;
    if (structured) {
        #pragma unroll 4
        for (int tt = 0; tt < CHUNK; ++tt) {
            const float dl = (float)delta[base + (size_t)tt * DIn];
            const float uu = (float)u[base + (size_t)tt * DIn];
            const float du = dl * uu;
            Ssum += dl;
            const half8 bv0 = *(const half8*)(Bp + tt * XPW);
            const half8 bv1 = *(const half8*)(Bp + tt * XPW + 8);
            float Bv[DSn];
            #pragma unroll
            for (int q = 0; q < 8; ++q) { Bv[q] = (float)bv0[q]; Bv[8 + q] = (float)bv1[q]; }
            const float e1 = __expf(dl * A0);
            const float e2 = e1 * e1, e4 = e2 * e2, e8 = e4 * e4;
            float E[DSn];
            E[0] = e1;      E[1] = e2;      E[2] = e2 * e1;  E[3] = e4;
            E[4] = e4 * e1; E[5] = e4 * e2; E[6] = E[5] * e1; E[7] = e8;
            E[8] = e8 * e1; E[9] = e8 * e2; E[10] = E[9] * e1; E[11] = e8 * e4;
            E[12] = E[11] * e1; E[13] = E[11] * e2; E[14] = E[13] * e1; E[15] = e8 * e8;
            #pragma unroll
            for (int s = 0; s < DSn; ++s) h[s] = E[s] * h[s] + du * Bv[s];
        }
    } else {
        #pragma unroll 4
        for (int tt = 0; tt < CHUNK; ++tt) {
            const float dl = (float)delta[base + (size_t)tt * DIn];
            const float uu = (float)u[base + (size_t)tt * DIn];
            const float du = dl * uu;
            Ssum += dl;
            const half8 bv0 = *(const half8*)(Bp + tt * XPW);
            const half8 bv1 = *(const half8*)(Bp + tt * XPW + 8);
            float Bv[DSn];
            #pragma unroll
            for (int q = 0; q < 8; ++q) { Bv[q] = (float)bv0[q]; Bv[8 + q] = (float)bv1[q]; }
            #pragma unroll
            for (int s = 0; s < DSn; ++s) h[s] = __expf(dl * A[s]) * h[s] + du * Bv[s];
        }
    }
    const size_t cidx = ((size_t)b * NCHUNK + c) * DIn + d;
    cS[cidx] = Ssum;
    half8 o0, o1;
    #pragma unroll
    for (int q = 0; q < 8; ++q) { o0[q] = (_Float16)h[q]; o1[q] = (_Float16)h[8 + q]; }
    *(half8*)(cH + cidx * DSn) = o0;
    *(half8*)(cH + cidx * DSn + 8) = o1;
}

// ------- combine: fold chunks + gate + weff dot + atomic out (proven) -------
__global__ __launch_bounds__(256)
void combine_v3(const float* __restrict__ cS, const _Float16* __restrict__ cH,
                const float* __restrict__ A_log, const float* __restrict__ Clast,
                const float* __restrict__ Dp, const _Float16* __restrict__ u,
                const float* __restrict__ zlast, const float* __restrict__ wp,
                float* __restrict__ out) {
    __shared__ float acc[16];
    const int tid = threadIdx.x;
    const int s = tid & 15;
    const int d = blockIdx.x * 16 + (tid >> 4);
    const int b = blockIdx.y;
    const float A = -__expf(A_log[(size_t)d * DSn + s]);
    float h = 0.f;
    const size_t cb0 = (size_t)b * NCHUNK;
    for (int c = 0; c < NCHUNK; ++c) {
        const size_t cidx = (cb0 + c) * DIn + d;
        h = __expf(A * cS[cidx]) * h + (float)cH[cidx * DSn + s];
    }
    float y = h * Clast[b * DSn + s];
    y += __shfl_xor(y, 1);
    y += __shfl_xor(y, 2);
    y += __shfl_xor(y, 4);
    y += __shfl_xor(y, 8);
    if (s == 0) {
        const float ul = (float)u[((size_t)b * Ln + (Ln - 1)) * DIn + d];
        float yy = y + Dp[d] * ul;
        yy *= silu_(zlast[(size_t)b * DIn + d]);
        float w = 0.f;
        #pragma unroll
        for (int c = 0; c < WCH; ++c) w += wp[(size_t)c * DIn + d];
        acc[tid >> 4] = yy * w;
    }
    __syncthreads();
    if (tid == 0) {
        float t = 0.f;
        #pragma unroll
        for (int i = 0; i < 16; ++i) t += acc[i];
        atomicAdd(&out[b], t);
    }
}

} // namespace

extern "C" void kernel_launch(void* const* d_in, const int* in_sizes, int n_in,
                              void* d_out, int out_size, void* d_ws, size_t ws_size,
                              hipStream_t stream) {
    (void)in_sizes; (void)n_in; (void)out_size; (void)ws_size;
    const float* x       = (const float*)d_in[0];
    const float* W_emb   = (const float*)d_in[1];
    const float* b_emb   = (const float*)d_in[2];
    const float* in_proj = (const float*)d_in[3];
    const float* conv_w  = (const float*)d_in[4];
    const float* conv_b  = (const float*)d_in[5];
    const float* x_proj  = (const float*)d_in[6];
    const float* dt_w    = (const float*)d_in[7];
    const float* dt_b    = (const float*)d_in[8];
    const float* A_log   = (const float*)d_in[9];
    const float* Dp      = (const float*)d_in[10];
    const float* out_w   = (const float*)d_in[11];
    const float* fc_w    = (const float*)d_in[12];
    const float* fc_b    = (const float*)d_in[13];
    float* out = (float*)d_out;
    char* w8 = (char*)d_ws;

    const size_t MB = 1ull << 20;
    _Float16* uh       = (_Float16*)(w8 + 16 * MB);  // 16 MB [upre_conv -> dtb/scan/combine]
    float*    wfoldP   = (float*)(w8 + 32 * MB);     // 16 MB [wfold -> skcomb]
    _Float16* deltah   = (_Float16*)(w8 + 32 * MB);  // aliases wfoldP [delta -> scan]
    float*    skp      = (float*)(w8 + 48 * MB);     // 10.5 MB [dtb -> skcombB]
    float*    cS       = skp;                        // aliases skp [scan -> combine]
    _Float16* cH       = (_Float16*)(w8 + 50 * MB);  // 16.8 MB [scan -> combine]
    _Float16* dtBh     = (_Float16*)(w8 + 67 * MB);
    _Float16* xh       = (_Float16*)(w8 + 68 * MB);
    _Float16* W_embT_h = (_Float16*)(w8 + 70 * MB);
    _Float16* in_projh = (_Float16*)(w8 + 71 * MB);  // 8 MB
    _Float16* xp_h     = (_Float16*)(w8 + 79 * MB);
    _Float16* dt_wh    = (_Float16*)(w8 + 80 * MB);
    _Float16* Wfoldh   = (_Float16*)(w8 + 81 * MB);  // 2 MB
    float*    wp       = (float*)(w8 + 83 * MB);
    float*    badd     = (float*)(w8 + 84 * MB);
    float*    zlast    = badd + 4096;
    float*    Clast    = zlast + (size_t)Bn * DIn;

    // 1. prep: conversions + weff + badd + out init
    prep_mega<<<6017, 256, 0, stream>>>(x, xh, in_proj, in_projh, dt_w, dt_wh,
                                        W_emb, W_embT_h, x_proj, xp_h,
                                        fc_w, out_w, wp, b_emb, badd, fc_b, out);
    // 2. Wfold = in_proj @ W_emb (split-K 4)
    skgemm2<<<dim3(4, ML / 128, 2), 256, 0, stream>>>(
        in_projh, DMn, W_embT_h, DMn, wfoldP, INn, 256);
    // 3. Wfold partial sum -> fp16
    skcomb<<<(ML * INn + 255) / 256, 256, 0, stream>>>(wfoldP, Wfoldh, ML * INn, 4);
    // 4. fused: upre GEMM (halo) -> LDS -> conv+silu -> uh ; + zlast GEMV
    upre_conv_zlast<<<dim3(17, ML / 128), 256, 0, stream>>>(
        xh, Wfoldh, badd, conv_w, conv_b, uh, x, zlast);
    // 5. dtB partials = uh @ xp^T (split-K 8)
    skgemm2<<<dim3(8, ML / 128, 1), 256, 0, stream>>>(uh, DIn, xp_h, DIn, skp, XPW, 256);
    // 6. dtB partial sum -> fp16 + C_last
    skcombB_clast<<<1296, 256, 0, stream>>>(skp, dtBh, uh, x_proj, Clast);
    // 7. delta = fp16(softplus(dtB @ dt_w^T + dt_b))  (deltah aliases wfoldP, dead now)
    hgemm_delta<<<dim3(DIn / 128, ML / 128), 256, 0, stream>>>(dtBh, dt_wh, dt_b, deltah);
    // 8. chunked scan (cS aliases skp, dead now)
    scan_chunk_kernel<<<dim3(DIn / 256, NCHUNK, Bn), 256, 0, stream>>>(
        deltah, uh, dtBh, A_log, cS, cH);
    // 9. combine + gate + weff dot + atomic out
    combine_v3<<<dim3(DIn / 16, Bn), 256, 0, stream>>>(
        cS, cH, A_log, Clast, Dp, uh, zlast, wp, out);
}